// Round 12
// baseline (25100.096 us; speedup 1.0000x reference)
//
#include <hip/hip_runtime.h>
#include <hip/hip_bf16.h>

typedef __attribute__((ext_vector_type(8))) short bf16x8;
typedef __attribute__((ext_vector_type(4))) float f32x4;
typedef __attribute__((ext_vector_type(4))) float fvec4;
typedef __attribute__((ext_vector_type(4))) unsigned short u16x4;
typedef __attribute__((ext_vector_type(4))) int i32x4;
typedef __attribute__((ext_vector_type(2))) unsigned int u32x2;

#define DEVI __device__ __forceinline__

constexpr int BB = 256, TT = 1024, FF = 128, HH = 512, OO = 64;
constexpr int KK = 256;    // fused input width [x_imp | m]
constexpr int NN = 2048;   // fused gate width  [z | r | htilde | gamma_h]

DEVI unsigned short f2bf(float x) {
  unsigned int u = __float_as_uint(x);
  u += 0x7FFFu + ((u >> 16) & 1u);          // RNE
  return (unsigned short)(u >> 16);
}
DEVI float bf2f(unsigned short s) {
  return __uint_as_float(((unsigned int)s) << 16);
}

DEVI void gload16(const void* g, void* lds) {
  __builtin_amdgcn_global_load_lds(
      (const __attribute__((address_space(1))) void*)g,
      (__attribute__((address_space(3))) void*)lds, 16, 0, 0);
}

DEVI void barrier_lds() {       // raw barrier: waits LDS ops only, vmcnt SURVIVES
  asm volatile("s_waitcnt lgkmcnt(0)" ::: "memory");
  __builtin_amdgcn_s_barrier();
  __builtin_amdgcn_sched_barrier(0);
}

// slabHG address swizzle (shorts): involution within a row, applied on BOTH
// the stage source and every read/write.
DEVI int hgIdx(int row, int c) { return row*1024 + (c ^ ((row & 7) << 3)); }

// ---------------------------------------------------------------------------
// K0a: per-column scales s_n = max_k |U[k][n]|  (z:0..511, r:512..1023, h:1024..1535)
// ---------------------------------------------------------------------------
__global__ __launch_bounds__(256) void prep_scales_kernel(
    const float* __restrict__ U_z, const float* __restrict__ U_r,
    const float* __restrict__ Uh, float* __restrict__ uscale)
{
  int n = blockIdx.x * 256 + threadIdx.x;
  if (n >= 1536) return;
  const float* src = (n < 512) ? U_z : (n < 1024) ? U_r : Uh;
  int col = n & 511;
  float s = 0.f;
  for (int k = 0; k < HH; ++k) s = fmaxf(s, fabsf(src[k*HH + col]));
  uscale[n] = fmaxf(s, 1e-30f);
}

// ---------------------------------------------------------------------------
// K0b: pack weights.
//   BwT [2048][256] bf16, bias[2048] f32 (as before)
//   UzrN u4 [16 u][8 wv][4 i][64 l][2 c] words (unit u = kt*2+half; half0=Uz)
//   UhN  u4 [ 8 u][8 wv][4 i][64 l][2 c] words (unit u = kt)
//   Word (…,c): nibble p = value q+8 at j = c*8 + (p&1)*4 + (p>>1),
//   k = base_k + (l>>4)*16 + j, col = (wv*4+i)*16 + (l&15),
//   q = clamp(round(U/s_col*7), -7, 7). Unpack = W&0x0F0F0F0F / (W>>4)&…
// ---------------------------------------------------------------------------
__global__ __launch_bounds__(256) void prep_kernel(
    const float* __restrict__ W_z, const float* __restrict__ V_z, const float* __restrict__ b_z,
    const float* __restrict__ W_r, const float* __restrict__ V_r, const float* __restrict__ b_r,
    const float* __restrict__ Wh,  const float* __restrict__ Vh,  const float* __restrict__ bh,
    const float* __restrict__ Wgh, const float* __restrict__ bgh,
    const float* __restrict__ U_z, const float* __restrict__ U_r, const float* __restrict__ Uh,
    const float* __restrict__ uscale,
    unsigned short* __restrict__ BwT, float* __restrict__ bias,
    unsigned int* __restrict__ UzrN, unsigned int* __restrict__ UhN)
{
  int idx = blockIdx.x * 256 + threadIdx.x;
  if (idx < 524288) {                       // BwT
    int n = idx >> 8, k = idx & 255;
    float v;
    if (n < 512)       { int h = n;        v = (k < 128) ? W_z[k*HH + h] : -V_z[(k-128)*HH + h]; }
    else if (n < 1024) { int h = n - 512;  v = (k < 128) ? W_r[k*HH + h] : -V_r[(k-128)*HH + h]; }
    else if (n < 1536) { int h = n - 1024; v = (k < 128) ? Wh [k*HH + h] : -Vh [(k-128)*HH + h]; }
    else               { int h = n - 1536; v = (k < 128) ? 0.f : Wgh[(k-128)*HH + h]; }
    BwT[n*256 + k] = f2bf(v);
    return;
  }
  idx -= 524288;
  if (idx < 2048) {                         // bias
    int n = idx; float v;
    if (n < 512)       { float s = b_z[n];      for (int f = 0; f < FF; ++f) s += V_z[f*HH + n];        v = s; }
    else if (n < 1024) { int h = n-512;  float s = b_r[h]; for (int f = 0; f < FF; ++f) s += V_r[f*HH + h]; v = s; }
    else if (n < 1536) { int h = n-1024; float s = bh[h];  for (int f = 0; f < FF; ++f) s += Vh[f*HH + h];  v = s; }
    else               { v = bgh[n-1536]; }
    bias[n] = v;
    return;
  }
  idx -= 2048;
  if (idx < 65536) {                        // UzrN words (i4, permuted, +8)
    int c  = idx & 1;
    int l  = (idx >> 1) & 63;
    int i  = (idx >> 7) & 3;
    int wv = (idx >> 9) & 7;
    int u  = idx >> 12;                    // 0..15
    int kt = u >> 1, half = u & 1;
    int col = (wv*4 + i)*16 + (l & 15);
    const float* src = half ? U_r : U_z;
    float sc = 7.f / uscale[half*512 + col];
    unsigned int word = 0;
#pragma unroll
    for (int p = 0; p < 8; ++p) {
      int j = c*8 + (p & 1)*4 + (p >> 1);
      int k = kt*64 + (l >> 4)*16 + j;
      float q = fminf(fmaxf(rintf(src[k*HH + col] * sc), -7.f), 7.f);
      unsigned int uq = (unsigned int)((int)q + 8);
      word |= (uq & 0xF) << (4*p);
    }
    UzrN[idx] = word;
    return;
  }
  idx -= 65536;
  if (idx < 32768) {                        // UhN words (i4, permuted, +8)
    int c  = idx & 1;
    int l  = (idx >> 1) & 63;
    int i  = (idx >> 7) & 3;
    int wv = (idx >> 9) & 7;
    int u  = idx >> 12;                    // 0..7 (kt)
    int col = (wv*4 + i)*16 + (l & 15);
    float sc = 7.f / uscale[1024 + col];
    unsigned int word = 0;
#pragma unroll
    for (int p = 0; p < 8; ++p) {
      int j = c*8 + (p & 1)*4 + (p >> 1);
      int k = u*64 + (l >> 4)*16 + j;
      float q = fminf(fmaxf(rintf(Uh[k*HH + col] * sc), -7.f), 7.f);
      unsigned int uq = (unsigned int)((int)q + 8);
      word |= (uq & 0xF) << (4*p);
    }
    UhN[idx] = word;
  }
}

// ---------------------------------------------------------------------------
// K1: imputation + fused A chunk [B*TC][256] bf16 = [x_imp | m]
// ---------------------------------------------------------------------------
__global__ __launch_bounds__(256) void build_A_kernel(
    const float* __restrict__ x, const float* __restrict__ delta,
    const float* __restrict__ mm, const float* __restrict__ xf,
    const float* __restrict__ Wgx, const float* __restrict__ bgx,
    const int* __restrict__ bs, unsigned short* __restrict__ A,
    int t0, int TC)
{
  int blk = blockIdx.x;
  int row8 = blk * 8;
  int b0  = row8 / TC;
  int tl0 = row8 % TC;
  if (b0 >= bs[t0 + tl0]) return;
  int tid = threadIdx.x;
  int rl = row8 + (tid >> 5);
  int tc = tl0 + (tid >> 5);
  long gi = ((long)b0*TT + t0 + tc) * 32 + (tid & 31);
  int f0 = (tid & 31) * 4;
  fvec4 xv = ((const fvec4*)x)[gi];
  fvec4 dv = ((const fvec4*)delta)[gi];
  fvec4 mv = ((const fvec4*)mm)[gi];
  fvec4 fv = ((const fvec4*)xf)[gi];
  unsigned short ox[4], om[4];
#pragma unroll
  for (int j = 0; j < 4; ++j) {
    float g  = __expf(-fmaxf(dv[j]*Wgx[f0+j] + bgx[f0+j], 0.f));
    float xr = g*fv[j] + (1.f - g)*0.001f;
    float xi = (mv[j] > 0.5f) ? xr : xv[j];
    ox[j] = f2bf(xi); om[j] = f2bf(mv[j]);
  }
  *(u16x4*)(A + (long)rl*KK + f0)       = (u16x4){ox[0], ox[1], ox[2], ox[3]};
  *(u16x4*)(A + (long)rl*KK + 128 + f0) = (u16x4){om[0], om[1], om[2], om[3]};
}

// ---------------------------------------------------------------------------
// K2: chunk GEMM  PRE[m][n] = A[m][:] @ Bw[:,n] + bias[n]  (bf16 MFMA, K=256)
// ---------------------------------------------------------------------------
__global__ __launch_bounds__(256) void gemm1_kernel(
    const unsigned short* __restrict__ A, const unsigned short* __restrict__ BwT,
    const float* __restrict__ bias, const int* __restrict__ bs,
    unsigned short* __restrict__ PRE, int t0, int TC)
{
  int blk = blockIdx.x;
  int nt = blk & 15;
  int mt = blk >> 4;
  {
    int m0 = mt * 128;
    int b_ = m0 / TC;
    int bcheck = (TC >= 128) ? bs[t0 + (m0 % TC)] : bs[t0];
    if (b_ >= bcheck) return;
  }
  int tid = threadIdx.x;
  int w = tid >> 6, l = tid & 63;
  int wm = w >> 1, wn = w & 1;
  int lr = l & 15, lg = l >> 4;
  int m_base = mt*128 + wm*64;
  int n_base = nt*128 + wn*64;
  const unsigned short* Aptr = A   + (long)(m_base + lr)*KK + lg*8;
  const unsigned short* Bptr = BwT + (long)(n_base + lr)*KK + lg*8;
  f32x4 acc[4][4];
#pragma unroll
  for (int i = 0; i < 4; ++i)
#pragma unroll
    for (int j = 0; j < 4; ++j) acc[i][j] = (f32x4){0.f, 0.f, 0.f, 0.f};

#pragma unroll
  for (int kt = 0; kt < 8; ++kt) {
    bf16x8 af[4], bfr[4];
#pragma unroll
    for (int i = 0; i < 4; ++i) af[i]  = *(const bf16x8*)(Aptr + (long)i*16*KK + kt*32);
#pragma unroll
    for (int i = 0; i < 4; ++i) bfr[i] = *(const bf16x8*)(Bptr + (long)i*16*KK + kt*32);
#pragma unroll
    for (int ms = 0; ms < 4; ++ms)
#pragma unroll
      for (int ns = 0; ns < 4; ++ns)
        acc[ms][ns] = __builtin_amdgcn_mfma_f32_16x16x32_bf16(af[ms], bfr[ns], acc[ms][ns], 0, 0, 0);
  }
#pragma unroll
  for (int ms = 0; ms < 4; ++ms) {
    int gm0 = m_base + ms*16 + lg*4;
#pragma unroll
    for (int ns = 0; ns < 4; ++ns) {
      int gn = n_base + ns*16 + lr;
      float bv = bias[gn];
      bool is_gamma = (gn >= 1536);
#pragma unroll
      for (int q = 0; q < 4; ++q) {
        float v = acc[ms][ns][q] + bv;
        if (is_gamma) v = __expf(-fmaxf(v, 0.f));
        PRE[(long)(gm0 + q)*NN + gn] = f2bf(v);
      }
    }
  }
}

// ---------------------------------------------------------------------------
// K3: sequential scan, 16 blocks x 512 threads (8 waves), i8 MFMA (K=64).
//   ALL U register-streamed as int4 nibbles (+8 offset): z/r depth-4 ring,
//   Uh depth-2 ring (read-to-locals then refill). Only HG slab uses glds;
//   S1 = wave-local vmcnt(0) BEFORE s_barrier (cross-wave glds visibility).
//   No per-unit asm waits: compiler tracks all register loads. Offset
//   corrected exactly via rowsum(hd_q)/rowsum(a2_q). 448 KB/step stream.
// ---------------------------------------------------------------------------
__global__ __launch_bounds__(512, 2) void scan_kernel(
    const unsigned short* __restrict__ PRE,
    const unsigned int* __restrict__ UzrN,
    const unsigned int* __restrict__ UhN,
    const float* __restrict__ uscale,
    const int* __restrict__ bs,
    float* __restrict__ h_st,
    float* __restrict__ sbuf,
    int t0, int TC)
{
  __shared__ __align__(16) i32x4 hd_l[8*64];               // 8 KB hd / a2 frags
  __shared__ __align__(16) unsigned short slabHG[16*1024]; // 32 KB [row][htld|r : gamma]
  __shared__ float hm[16][524];                            // 33.5 KB h master
  __shared__ int hsumW[8][16];                             // hd rowsum partials
  __shared__ int hsumW2[8][16];                            // a2 rowsum partials
  __shared__ float wmax[8];

  const int tid = threadIdx.x;
  const int r0 = blockIdx.x * 16;
  if (t0 > 0 && bs[t0] <= r0) return;

  const int w = tid >> 6, l = tid & 63, lr = l & 15, lg = l >> 4;
  const size_t rowStr = (size_t)TC * NN;

  auto STAGEHG = [&](const unsigned short* PREn) {  // htilde+gamma halves, swizzled source
#pragma unroll
    for (int j = 0; j < 4; ++j) {
      int idx = w*4 + j;
      int row = idx >> 1;
      int phys = (idx & 1)*512 + l*8;
      int logi = phys ^ ((row & 7) << 3);
      const unsigned short* src = PREn + (size_t)row*rowStr + 1024 + logi;
      gload16(src, &slabHG[idx*512]);
    }
  };
  auto LOADZR = [&](int u, u32x2* d) {   // z/r unit u: 4 tiles x 8B per thread
#pragma unroll
    for (int i = 0; i < 4; ++i)
      d[i] = ((const u32x2*)UzrN)[(u*8 + w)*256 + i*64 + l];
  };
  auto LOADB = [&](int u, u32x2* d) {    // Uh unit u: 4 tiles x 8B per thread
#pragma unroll
    for (int i = 0; i < 4; ++i)
      d[i] = ((const u32x2*)UhN)[(u*8 + w)*256 + i*64 + l];
  };

  // per-thread dequant constants
  float zdq[4], rdq[4], hdq[4];
#pragma unroll
  for (int i = 0; i < 4; ++i) {
    int c = (w*4 + i)*16 + lr;
    zdq[i] = uscale[c]        * (1.f/889.f);    // 7 * 127
    rdq[i] = uscale[512 + c]  * (1.f/889.f);
    hdq[i] = uscale[1024 + c] * (1.f/889.f);
  }
  if (tid < 8) wmax[tid] = (t0 == 0) ? 1e-20f : sbuf[blockIdx.x];

  if (t0 == 0) {
    for (int i = tid; i < 16*512; i += 512) hm[i>>9][i&511] = 0.f;
  } else {
    for (int i = tid; i < 16*512; i += 512)
      hm[i>>9][i&511] = h_st[(size_t)(r0 + (i>>9))*HH + (i&511)];
  }
  asm volatile("s_waitcnt vmcnt(0)" ::: "memory");  // hm loads fully done
  __builtin_amdgcn_sched_barrier(0);

  // prologue: stage HG for step 0 (only glds in FIFO)
  STAGEHG(PRE + (size_t)r0*TC*NN);

  u32x2 inZ[4][4];   // z/r depth-4 ring
  u32x2 inB[2][4];   // Uh depth-2 ring

  for (int tc = 0; tc < TC; ++tc) {
    const int bsv = bs[t0 + tc];
    if (bsv <= r0) break;                  // descending bs: done forever
    const int na = min(16, bsv - r0);
    const unsigned short* PREstep = PRE + ((size_t)r0*TC + tc)*NN;
    const unsigned short* PREnext = PREstep + NN;

    // S1: own glds landed BEFORE barrier -> all waves' HG visible after it
    asm volatile("s_waitcnt lgkmcnt(0)" ::: "memory");
    asm volatile("s_waitcnt vmcnt(0)" ::: "memory");
    __builtin_amdgcn_s_barrier();
    __builtin_amdgcn_sched_barrier(0);

    // dynamic quant scale for hd (exact bound: |hd| <= max|h| = s)
    float s = wmax[0];
#pragma unroll
    for (int i = 1; i < 8; ++i) s = fmaxf(s, wmax[i]);
    const float qs = 127.f / s;

    // pz/pr clump (VGPR loads, consumed in epilogue A)
    unsigned short pzr[2][4][4];
#pragma unroll
    for (int i = 0; i < 4; ++i)
#pragma unroll
      for (int q = 0; q < 4; ++q) {
        int row = lg*4 + q, col = (w*4 + i)*16 + lr;
        const unsigned short* pb = PREstep + (size_t)row*rowStr + col;
        pzr[0][i][q] = pb[0];
        pzr[1][i][q] = pb[512];
      }

    // prefetch z/r units 0..3 into ring
    LOADZR(0, inZ[0]); LOADZR(1, inZ[1]);
    LOADZR(2, inZ[2]); LOADZR(3, inZ[3]);

    // hd build (kt = w): quantize (act? gamma*h : h) to i8 frags + rowsum
    // (no clamp: |hd| <= s exactly, so |hd*qs| <= 127)
    i32x4 qwReg;
    {
      const int k0 = w*64 + lg*16;
      const bool act = lr < na;
      bf16x8 g0 = *(const bf16x8*)&slabHG[hgIdx(lr, 512 + k0)];
      bf16x8 g1 = *(const bf16x8*)&slabHG[hgIdx(lr, 512 + k0 + 8)];
      int psum = 0;
#pragma unroll
      for (int d = 0; d < 4; ++d) {
        int word = 0;
#pragma unroll
        for (int b = 0; b < 4; ++b) {
          int j = d*4 + b;
          float h  = hm[lr][k0 + j];
          float gv = bf2f((unsigned short)(j < 8 ? g0[j] : g1[j-8]));
          float hd = act ? gv*h : h;
          int qi = (int)rintf(hd*qs);
          psum += qi;
          word |= (qi & 0xFF) << (8*b);
        }
        qwReg[d] = word;
      }
      hd_l[w*64 + l] = qwReg;
      psum += __shfl_xor(psum, 16);
      psum += __shfl_xor(psum, 32);
      if (lg == 0) hsumW[w][lr] = psum;    // wave w's k-range [64w, 64w+64)
    }

    // hoist htilde-preact + gamma (slab overwritten by next-step staging)
    float phv[4][4], ggv[4][4];
#pragma unroll
    for (int i = 0; i < 4; ++i)
#pragma unroll
      for (int q = 0; q < 4; ++q) {
        int row = lg*4 + q, col = (w*4 + i)*16 + lr;
        phv[i][q] = bf2f(slabHG[hgIdx(row, col)]);
        ggv[i][q] = bf2f(slabHG[hgIdx(row, 512 + col)]);
      }
    barrier_lds();                         // S2: hd_l + hsumW ready

    // ---- phase A: z|r, 16 units, depth-4 register ring ----
    i32x4 acc[8];
#pragma unroll
    for (int i = 0; i < 8; ++i) acc[i] = (i32x4){0, 0, 0, 0};
    i32x4 af;
#pragma unroll
    for (int u = 0; u < 16; ++u) {
      if (!(u & 1)) af = hd_l[(u>>1)*64 + l];
      u32x2 cur[4];
#pragma unroll
      for (int i = 0; i < 4; ++i) cur[i] = inZ[u & 3][i];
      if (u < 12)       LOADZR(u + 4, inZ[u & 3]);
      else if (u == 14) LOADB(0, inB[0]);
      else if (u == 15) LOADB(1, inB[1]);
      __builtin_amdgcn_s_setprio(1);
#pragma unroll
      for (int i = 0; i < 4; ++i) {
        unsigned int W0 = cur[i][0], W1 = cur[i][1];
        i32x4 bfr;
        bfr[0] = (int)(W0 & 0x0F0F0F0Fu);
        bfr[1] = (int)((W0 >> 4) & 0x0F0F0F0Fu);
        bfr[2] = (int)(W1 & 0x0F0F0F0Fu);
        bfr[3] = (int)((W1 >> 4) & 0x0F0F0F0Fu);
        acc[(u&1)*4 + i] = __builtin_amdgcn_mfma_i32_16x16x64_i8(af, bfr, acc[(u&1)*4 + i], 0, 0, 0);
      }
      __builtin_amdgcn_s_setprio(0);
    }

    // epilogue A: offset-correct, z -> regs; r -> slabHG (cols 0..511)
    int rsum[4];
#pragma unroll
    for (int q = 0; q < 4; ++q) {
      int row = lg*4 + q, t = 0;
#pragma unroll
      for (int w2 = 0; w2 < 8; ++w2) t += hsumW[w2][row];
      rsum[q] = t * 8;
    }
    float zreg[4][4];
#pragma unroll
    for (int i = 0; i < 4; ++i)
#pragma unroll
      for (int q = 0; q < 4; ++q) {
        int row = lg*4 + q, col = (w*4 + i)*16 + lr;
        float az = bf2f(pzr[0][i][q]) + (float)(acc[i][q]   - rsum[q]) * zdq[i] * s;
        float ar = bf2f(pzr[1][i][q]) + (float)(acc[4+i][q] - rsum[q]) * rdq[i] * s;
        zreg[i][q] = 1.f/(1.f + __expf(-az));
        slabHG[hgIdx(row, col)] = f2bf(1.f/(1.f + __expf(-ar)));
      }
    barrier_lds();                         // S3: r ready; phase-A hd_l reads done

    // a2 = hd*r quantized (register hd; |hd_q*r| <= 127, no clamp) + rowsum
    {
      const int k0 = w*64 + lg*16;
      bf16x8 r0v = *(const bf16x8*)&slabHG[hgIdx(lr, k0)];
      bf16x8 r1v = *(const bf16x8*)&slabHG[hgIdx(lr, k0 + 8)];
      i32x4 nw;
      int psum2 = 0;
#pragma unroll
      for (int d = 0; d < 4; ++d) {
        int word = qwReg[d], out = 0;
#pragma unroll
        for (int b = 0; b < 4; ++b) {
          int j = d*4 + b;
          int hq = (int)(signed char)((word >> (8*b)) & 0xFF);
          float rv = bf2f((unsigned short)(j < 8 ? r0v[j] : r1v[j-8]));
          int qi = (int)rintf((float)hq * rv);
          psum2 += qi;
          out |= (qi & 0xFF) << (8*b);
        }
        nw[d] = out;
      }
      hd_l[w*64 + l] = nw;
      psum2 += __shfl_xor(psum2, 16);
      psum2 += __shfl_xor(psum2, 32);
      if (lg == 0) hsumW2[w][lr] = psum2;
    }
    barrier_lds();                         // S4: a2 frags + hsumW2 ready

    // ---- phase B: htilde, 8 units, depth-2 register ring ----
    i32x4 accB[4];
#pragma unroll
    for (int i = 0; i < 4; ++i) accB[i] = (i32x4){0, 0, 0, 0};
#pragma unroll
    for (int u = 0; u < 8; ++u) {
      u32x2 cur[4];
#pragma unroll
      for (int i = 0; i < 4; ++i) cur[i] = inB[u & 1][i];
      if (u < 6)       LOADB(u + 2, inB[u & 1]);
      if (u == 4)      STAGEHG(PREnext);   // next step's slab
      i32x4 af2 = hd_l[u*64 + l];
      __builtin_amdgcn_s_setprio(1);
#pragma unroll
      for (int i = 0; i < 4; ++i) {
        unsigned int W0 = cur[i][0], W1 = cur[i][1];
        i32x4 bfr;
        bfr[0] = (int)(W0 & 0x0F0F0F0Fu);
        bfr[1] = (int)((W0 >> 4) & 0x0F0F0F0Fu);
        bfr[2] = (int)(W1 & 0x0F0F0F0Fu);
        bfr[3] = (int)((W1 >> 4) & 0x0F0F0F0Fu);
        accB[i] = __builtin_amdgcn_mfma_i32_16x16x64_i8(af2, bfr, accB[i], 0, 0, 0);
      }
      __builtin_amdgcn_s_setprio(0);
    }

    // epilogue B: h update + block max|h| for next step's quant scale
    int rsum2[4];
#pragma unroll
    for (int q = 0; q < 4; ++q) {
      int row = lg*4 + q, t = 0;
#pragma unroll
      for (int w2 = 0; w2 < 8; ++w2) t += hsumW2[w2][row];
      rsum2[q] = t * 8;
    }
    float mloc = 0.f;
#pragma unroll
    for (int i = 0; i < 4; ++i)
#pragma unroll
      for (int q = 0; q < 4; ++q) {
        int row = lg*4 + q, col = (w*4 + i)*16 + lr;
        float hval;
        if (row < na) {
          float ah = phv[i][q] + (float)(accB[i][q] - rsum2[q]) * hdq[i] * s;
          float e  = __expf(2.f*ah);
          float th = 1.f - 2.f/(e + 1.f);          // tanh, overflow-safe
          float hd = ggv[i][q] * hm[row][col];
          hval = hd + zreg[i][q]*(th - hd);
          hm[row][col] = hval;
        } else {
          hval = hm[row][col];
        }
        mloc = fmaxf(mloc, fabsf(hval));
      }
#pragma unroll
    for (int off = 32; off > 0; off >>= 1) mloc = fmaxf(mloc, __shfl_xor(mloc, off));
    if (l == 0) wmax[w] = fmaxf(mloc, 1e-20f);
  }

  asm volatile("s_waitcnt vmcnt(0)" ::: "memory");  // drain stray prefetches
  barrier_lds();
  for (int i = tid; i < 16*512; i += 512)
    h_st[(size_t)(r0 + (i>>9))*HH + (i&511)] = hm[i>>9][i&511];
  if (tid == 0) {
    float s = wmax[0];
#pragma unroll
    for (int i = 1; i < 8; ++i) s = fmaxf(s, wmax[i]);
    sbuf[blockIdx.x] = s;
  }
}

// ---------------------------------------------------------------------------
// K4: head: eval BatchNorm + decoder GEMV + log_softmax.
//   d_out = [output (256x64) | h_bn (256x512)] fp32
// ---------------------------------------------------------------------------
__global__ __launch_bounds__(64) void head_kernel(
    const float* __restrict__ h_state, const float* __restrict__ decW,
    const float* __restrict__ decb, const float* __restrict__ bnw,
    const float* __restrict__ bnb, float* __restrict__ out)
{
  int b = blockIdx.x, o = threadIdx.x;
  __shared__ float hbn[HH];
  const float s = rsqrtf(1.f + 1e-5f);
  for (int j = o; j < HH; j += 64)
    hbn[j] = h_state[(long)b*HH + j] * (bnw[j] * s) + bnb[j];
  __syncthreads();
  float acc = decb[o];
  for (int j = 0; j < HH; ++j) acc += hbn[j] * decW[j*OO + o];
  float mx = acc;
#pragma unroll
  for (int off = 32; off > 0; off >>= 1) mx = fmaxf(mx, __shfl_xor(mx, off));
  float ex = __expf(acc - mx);
  float sum = ex;
#pragma unroll
  for (int off = 32; off > 0; off >>= 1) sum += __shfl_xor(sum, off);
  out[(long)b*OO + o] = acc - mx - __logf(sum);
  for (int j = o; j < HH; j += 64)
    out[(long)BB*OO + (long)b*HH + j] = hbn[j];
}

// ---------------------------------------------------------------------------
extern "C" void kernel_launch(void* const* d_in, const int* in_sizes, int n_in,
                              void* d_out, int out_size, void* d_ws, size_t ws_size,
                              hipStream_t stream) {
  const float* x     = (const float*)d_in[0];
  const float* delta = (const float*)d_in[1];
  const float* mm    = (const float*)d_in[2];
  const float* xf    = (const float*)d_in[3];
  const int*   bs    = (const int*)  d_in[4];
  const float* W_r   = (const float*)d_in[5];
  const float* U_r   = (const float*)d_in[6];
  const float* V_r   = (const float*)d_in[7];
  const float* b_r   = (const float*)d_in[8];
  const float* W_z   = (const float*)d_in[9];
  const float* U_z   = (const float*)d_in[10];
  const float* V_z   = (const float*)d_in[11];
  const float* b_z   = (const float*)d_in[12];
  const float* W     = (const float*)d_in[13];
  const float* U     = (const float*)d_in[14];
  const float* V     = (const float*)d_in[15];
  const float* b     = (const float*)d_in[16];
  const float* Wgx   = (const float*)d_in[17];
  const float* bgx   = (const float*)d_in[18];
  const float* Wgh   = (const float*)d_in[19];
  const float* bgh   = (const float*)d_in[20];
  const float* decW  = (const float*)d_in[21];
  const float* decb  = (const float*)d_in[22];
  const float* bnw   = (const float*)d_in[23];
  const float* bnb   = (const float*)d_in[24];

  auto rnd = [](size_t v) { return (v + 255) & ~(size_t)255; };
  const size_t fixed_bytes = rnd((size_t)2048*256*2) + rnd(2048*4)
                           + rnd((size_t)256*1024) + rnd((size_t)128*1024)
                           + rnd(1536*4) + rnd(64)
                           + rnd((size_t)BB*HH*4);
  int TC = 0;
  const int cands[5] = {128, 64, 32, 16, 8};
  for (int i = 0; i < 5; ++i) {
    size_t need = fixed_bytes + rnd((size_t)BB*cands[i]*KK*2) + rnd((size_t)BB*cands[i]*NN*2);
    if (need <= ws_size) { TC = cands[i]; break; }
  }
  if (TC == 0) return;

  char* p = (char*)d_ws;
  auto alloc = [&](size_t bytes) { char* r = p; p += (bytes + 255) & ~(size_t)255; return r; };
  unsigned short* A_chunk = (unsigned short*)alloc((size_t)BB * TC * KK * 2);
  unsigned short* PREc    = (unsigned short*)alloc((size_t)BB * TC * NN * 2);
  unsigned short* BwT     = (unsigned short*)alloc((size_t)2048 * 256 * 2);
  float*          bias    = (float*)alloc(2048 * 4);
  unsigned int*   UzrN    = (unsigned int*)alloc((size_t)256 * 1024);
  unsigned int*   UhN     = (unsigned int*)alloc((size_t)128 * 1024);
  float*          uscale  = (float*)alloc(1536 * 4);
  float*          sbuf    = (float*)alloc(64);
  float*          h_st    = (float*)alloc((size_t)BB * HH * 4);

  prep_scales_kernel<<<6, 256, 0, stream>>>(U_z, U_r, U, uscale);
  prep_kernel<<<2440, 256, 0, stream>>>(W_z, V_z, b_z, W_r, V_r, b_r, W, V, b,
                                        Wgh, bgh, U_z, U_r, U, uscale,
                                        BwT, bias, UzrN, UhN);
  const int nch = TT / TC;
  for (int c = 0; c < nch; ++c) {
    int t0 = c * TC;
    build_A_kernel<<<BB*TC/8, 256, 0, stream>>>(x, delta, mm, xf, Wgx, bgx, bs,
                                                A_chunk, t0, TC);
    gemm1_kernel<<<(BB*TC/128)*16, 256, 0, stream>>>(A_chunk, BwT, bias, bs,
                                                     PREc, t0, TC);
    scan_kernel<<<16, 512, 0, stream>>>(PREc, UzrN, UhN, uscale, bs,
                                        h_st, sbuf, t0, TC);
  }
  head_kernel<<<256, 64, 0, stream>>>(h_st, decW, decb, bnw, bnb, (float*)d_out);
}

// Round 13
// 23181.677 us; speedup vs baseline: 1.0828x; 1.0828x over previous
//
#include <hip/hip_runtime.h>
#include <hip/hip_bf16.h>

typedef __attribute__((ext_vector_type(8))) short bf16x8;
typedef __attribute__((ext_vector_type(4))) float f32x4;
typedef __attribute__((ext_vector_type(4))) float fvec4;
typedef __attribute__((ext_vector_type(4))) unsigned short u16x4;
typedef __attribute__((ext_vector_type(4))) int i32x4;
typedef __attribute__((ext_vector_type(2))) unsigned int u32x2;

#define DEVI __device__ __forceinline__

constexpr int BB = 256, TT = 1024, FF = 128, HH = 512, OO = 64;
constexpr int KK = 256;    // fused input width [x_imp | m]
constexpr int NN = 2048;   // fused gate width  [z | r | htilde | gamma_h]

DEVI unsigned short f2bf(float x) {
  unsigned int u = __float_as_uint(x);
  u += 0x7FFFu + ((u >> 16) & 1u);          // RNE
  return (unsigned short)(u >> 16);
}
DEVI float bf2f(unsigned short s) {
  return __uint_as_float(((unsigned int)s) << 16);
}

DEVI void gload16(const void* g, void* lds) {
  __builtin_amdgcn_global_load_lds(
      (const __attribute__((address_space(1))) void*)g,
      (__attribute__((address_space(3))) void*)lds, 16, 0, 0);
}

DEVI void barrier_lds() {       // raw barrier: waits LDS ops only, vmcnt SURVIVES
  asm volatile("s_waitcnt lgkmcnt(0)" ::: "memory");
  __builtin_amdgcn_s_barrier();
  __builtin_amdgcn_sched_barrier(0);
}

// slabHG address swizzle (shorts): involution within a row, applied on BOTH
// the stage source and every read/write.
DEVI int hgIdx(int row, int c) { return row*1024 + (c ^ ((row & 7) << 3)); }

// ---------------------------------------------------------------------------
// K0a: per-column scales s_n = max_k |U[k][n]|  (z:0..511, r:512..1023, h:1024..1535)
// ---------------------------------------------------------------------------
__global__ __launch_bounds__(256) void prep_scales_kernel(
    const float* __restrict__ U_z, const float* __restrict__ U_r,
    const float* __restrict__ Uh, float* __restrict__ uscale)
{
  int n = blockIdx.x * 256 + threadIdx.x;
  if (n >= 1536) return;
  const float* src = (n < 512) ? U_z : (n < 1024) ? U_r : Uh;
  int col = n & 511;
  float s = 0.f;
  for (int k = 0; k < HH; ++k) s = fmaxf(s, fabsf(src[k*HH + col]));
  uscale[n] = fmaxf(s, 1e-30f);
}

// ---------------------------------------------------------------------------
// K0b: pack weights.
//   BwT [2048][256] bf16, bias[2048] f32 (as before)
//   UzrN u4 [16 u][32 t][64 l][2 c] words (unit u = kt*2+half; half0=Uz)
//   UhN  u4 [ 8 u][32 t][64 l][2 c] words (unit u = kt)
//   Word (…,c): nibble p = value q+8 at j = c*8 + (p&1)*4 + (p>>1),
//   k = base_k + (l>>4)*16 + j, col = t*16 + (l&15),
//   q = clamp(round(U/s_col*7), -7, 7). Unpack = W&0x0F0F0F0F / (W>>4)&…
// ---------------------------------------------------------------------------
__global__ __launch_bounds__(256) void prep_kernel(
    const float* __restrict__ W_z, const float* __restrict__ V_z, const float* __restrict__ b_z,
    const float* __restrict__ W_r, const float* __restrict__ V_r, const float* __restrict__ b_r,
    const float* __restrict__ Wh,  const float* __restrict__ Vh,  const float* __restrict__ bh,
    const float* __restrict__ Wgh, const float* __restrict__ bgh,
    const float* __restrict__ U_z, const float* __restrict__ U_r, const float* __restrict__ Uh,
    const float* __restrict__ uscale,
    unsigned short* __restrict__ BwT, float* __restrict__ bias,
    unsigned int* __restrict__ UzrN, unsigned int* __restrict__ UhN)
{
  int idx = blockIdx.x * 256 + threadIdx.x;
  if (idx < 524288) {                       // BwT
    int n = idx >> 8, k = idx & 255;
    float v;
    if (n < 512)       { int h = n;        v = (k < 128) ? W_z[k*HH + h] : -V_z[(k-128)*HH + h]; }
    else if (n < 1024) { int h = n - 512;  v = (k < 128) ? W_r[k*HH + h] : -V_r[(k-128)*HH + h]; }
    else if (n < 1536) { int h = n - 1024; v = (k < 128) ? Wh [k*HH + h] : -Vh [(k-128)*HH + h]; }
    else               { int h = n - 1536; v = (k < 128) ? 0.f : Wgh[(k-128)*HH + h]; }
    BwT[n*256 + k] = f2bf(v);
    return;
  }
  idx -= 524288;
  if (idx < 2048) {                         // bias
    int n = idx; float v;
    if (n < 512)       { float s = b_z[n];      for (int f = 0; f < FF; ++f) s += V_z[f*HH + n];        v = s; }
    else if (n < 1024) { int h = n-512;  float s = b_r[h]; for (int f = 0; f < FF; ++f) s += V_r[f*HH + h]; v = s; }
    else if (n < 1536) { int h = n-1024; float s = bh[h];  for (int f = 0; f < FF; ++f) s += Vh[f*HH + h];  v = s; }
    else               { v = bgh[n-1536]; }
    bias[n] = v;
    return;
  }
  idx -= 2048;
  if (idx < 65536) {                        // UzrN words (i4, permuted, +8)
    int c  = idx & 1;
    int l  = (idx >> 1) & 63;
    int t  = (idx >> 7) & 31;
    int u  = idx >> 12;                    // 0..15
    int kt = u >> 1, half = u & 1;
    int col = t*16 + (l & 15);
    const float* src = half ? U_r : U_z;
    float sc = 7.f / uscale[half*512 + col];
    unsigned int word = 0;
#pragma unroll
    for (int p = 0; p < 8; ++p) {
      int j = c*8 + (p & 1)*4 + (p >> 1);
      int k = kt*64 + (l >> 4)*16 + j;
      float q = fminf(fmaxf(rintf(src[k*HH + col] * sc), -7.f), 7.f);
      unsigned int uq = (unsigned int)((int)q + 8);
      word |= (uq & 0xF) << (4*p);
    }
    UzrN[idx] = word;
    return;
  }
  idx -= 65536;
  if (idx < 32768) {                        // UhN words (i4, permuted, +8)
    int c  = idx & 1;
    int l  = (idx >> 1) & 63;
    int t  = (idx >> 7) & 31;
    int u  = idx >> 12;                    // 0..7 (kt)
    int col = t*16 + (l & 15);
    float sc = 7.f / uscale[1024 + col];
    unsigned int word = 0;
#pragma unroll
    for (int p = 0; p < 8; ++p) {
      int j = c*8 + (p & 1)*4 + (p >> 1);
      int k = u*64 + (l >> 4)*16 + j;
      float q = fminf(fmaxf(rintf(Uh[k*HH + col] * sc), -7.f), 7.f);
      unsigned int uq = (unsigned int)((int)q + 8);
      word |= (uq & 0xF) << (4*p);
    }
    UhN[idx] = word;
  }
}

// ---------------------------------------------------------------------------
// K1: imputation + fused A chunk [B*TC][256] bf16 = [x_imp | m]
// ---------------------------------------------------------------------------
__global__ __launch_bounds__(256) void build_A_kernel(
    const float* __restrict__ x, const float* __restrict__ delta,
    const float* __restrict__ mm, const float* __restrict__ xf,
    const float* __restrict__ Wgx, const float* __restrict__ bgx,
    const int* __restrict__ bs, unsigned short* __restrict__ A,
    int t0, int TC)
{
  int blk = blockIdx.x;
  int row8 = blk * 8;
  int b0  = row8 / TC;
  int tl0 = row8 % TC;
  if (b0 >= bs[t0 + tl0]) return;
  int tid = threadIdx.x;
  int rl = row8 + (tid >> 5);
  int tc = tl0 + (tid >> 5);
  long gi = ((long)b0*TT + t0 + tc) * 32 + (tid & 31);
  int f0 = (tid & 31) * 4;
  fvec4 xv = ((const fvec4*)x)[gi];
  fvec4 dv = ((const fvec4*)delta)[gi];
  fvec4 mv = ((const fvec4*)mm)[gi];
  fvec4 fv = ((const fvec4*)xf)[gi];
  unsigned short ox[4], om[4];
#pragma unroll
  for (int j = 0; j < 4; ++j) {
    float g  = __expf(-fmaxf(dv[j]*Wgx[f0+j] + bgx[f0+j], 0.f));
    float xr = g*fv[j] + (1.f - g)*0.001f;
    float xi = (mv[j] > 0.5f) ? xr : xv[j];
    ox[j] = f2bf(xi); om[j] = f2bf(mv[j]);
  }
  *(u16x4*)(A + (long)rl*KK + f0)       = (u16x4){ox[0], ox[1], ox[2], ox[3]};
  *(u16x4*)(A + (long)rl*KK + 128 + f0) = (u16x4){om[0], om[1], om[2], om[3]};
}

// ---------------------------------------------------------------------------
// K2: chunk GEMM  PRE[m][n] = A[m][:] @ Bw[:,n] + bias[n]  (bf16 MFMA, K=256)
// ---------------------------------------------------------------------------
__global__ __launch_bounds__(256) void gemm1_kernel(
    const unsigned short* __restrict__ A, const unsigned short* __restrict__ BwT,
    const float* __restrict__ bias, const int* __restrict__ bs,
    unsigned short* __restrict__ PRE, int t0, int TC)
{
  int blk = blockIdx.x;
  int nt = blk & 15;
  int mt = blk >> 4;
  {
    int m0 = mt * 128;
    int b_ = m0 / TC;
    int bcheck = (TC >= 128) ? bs[t0 + (m0 % TC)] : bs[t0];
    if (b_ >= bcheck) return;
  }
  int tid = threadIdx.x;
  int w = tid >> 6, l = tid & 63;
  int wm = w >> 1, wn = w & 1;
  int lr = l & 15, lg = l >> 4;
  int m_base = mt*128 + wm*64;
  int n_base = nt*128 + wn*64;
  const unsigned short* Aptr = A   + (long)(m_base + lr)*KK + lg*8;
  const unsigned short* Bptr = BwT + (long)(n_base + lr)*KK + lg*8;
  f32x4 acc[4][4];
#pragma unroll
  for (int i = 0; i < 4; ++i)
#pragma unroll
    for (int j = 0; j < 4; ++j) acc[i][j] = (f32x4){0.f, 0.f, 0.f, 0.f};

#pragma unroll
  for (int kt = 0; kt < 8; ++kt) {
    bf16x8 af[4], bfr[4];
#pragma unroll
    for (int i = 0; i < 4; ++i) af[i]  = *(const bf16x8*)(Aptr + (long)i*16*KK + kt*32);
#pragma unroll
    for (int i = 0; i < 4; ++i) bfr[i] = *(const bf16x8*)(Bptr + (long)i*16*KK + kt*32);
#pragma unroll
    for (int ms = 0; ms < 4; ++ms)
#pragma unroll
      for (int ns = 0; ns < 4; ++ns)
        acc[ms][ns] = __builtin_amdgcn_mfma_f32_16x16x32_bf16(af[ms], bfr[ns], acc[ms][ns], 0, 0, 0);
  }
#pragma unroll
  for (int ms = 0; ms < 4; ++ms) {
    int gm0 = m_base + ms*16 + lg*4;
#pragma unroll
    for (int ns = 0; ns < 4; ++ns) {
      int gn = n_base + ns*16 + lr;
      float bv = bias[gn];
      bool is_gamma = (gn >= 1536);
#pragma unroll
      for (int q = 0; q < 4; ++q) {
        float v = acc[ms][ns][q] + bv;
        if (is_gamma) v = __expf(-fmaxf(v, 0.f));
        PRE[(long)(gm0 + q)*NN + gn] = f2bf(v);
      }
    }
  }
}

// ---------------------------------------------------------------------------
// K3: sequential scan, 16 blocks x 1024 threads (16 waves = 4 waves/SIMD).
//   r11 pipeline with doubled TLP: each wave owns 2 column-tiles. z/r via
//   depth-4 register ring; Uh via depth-4 glds slots with counted vmcnt
//   (1 glds/unit/wave); HG slab glds. hd/a2 frag builds on waves 0..7.
//   Offset corrected exactly via rowsum(hd_q)/rowsum(a2_q).
// ---------------------------------------------------------------------------
__global__ __launch_bounds__(1024) void scan_kernel(
    const unsigned short* __restrict__ PRE,
    const unsigned int* __restrict__ UzrN,
    const unsigned int* __restrict__ UhN,
    const float* __restrict__ uscale,
    const int* __restrict__ bs,
    float* __restrict__ h_st,
    float* __restrict__ sbuf,
    int t0, int TC)
{
  __shared__ __align__(16) char Ubuf[16][4][1024];         // 64 KB (4-slot Uh dbuf)
  __shared__ __align__(16) i32x4 hd_l[8*64];               // 8 KB hd / a2 frags
  __shared__ __align__(16) unsigned short slabHG[16*1024]; // 32 KB [row][htld|r : gamma]
  __shared__ float hm[16][524];                            // 33.5 KB h master
  __shared__ int hsumW[8][16];                             // hd rowsum partials
  __shared__ int hsumW2[8][16];                            // a2 rowsum partials
  __shared__ float wmax[16];

  const int tid = threadIdx.x;
  const int r0 = blockIdx.x * 16;
  if (t0 > 0 && bs[t0] <= r0) return;

  const int w = tid >> 6, l = tid & 63, lr = l & 15, lg = l >> 4;
  const size_t rowStr = (size_t)TC * NN;

  auto STAGEB = [&](int u) {   // Uh unit u, this wave's 2 tiles (1 KB): 1 glds
    const char* src = (const char*)UhN + ((size_t)(u*32 + w*2))*512 + (size_t)l*16;
    gload16(src, &Ubuf[w][u & 3][0]);
  };
  auto STAGEHG = [&](const unsigned short* PREn) {  // row w, both halves
#pragma unroll
    for (int j = 0; j < 2; ++j) {
      int phys = j*512 + l*8;
      int logi = phys ^ ((w & 7) << 3);
      const unsigned short* src = PREn + (size_t)w*rowStr + 1024 + logi;
      gload16(src, &slabHG[(w*2 + j)*512]);
    }
  };
  auto LOADZR = [&](int u, u32x2* d) {   // z/r unit u: this wave's 2 tiles
#pragma unroll
    for (int i = 0; i < 2; ++i)
      d[i] = ((const u32x2*)UzrN)[(u*32 + w*2 + i)*64 + l];
  };

  // per-thread dequant constants (2 tiles)
  float zdq[2], rdq[2], hdq[2];
#pragma unroll
  for (int i = 0; i < 2; ++i) {
    int c = (w*2 + i)*16 + lr;
    zdq[i] = uscale[c]        * (1.f/889.f);    // 7 * 127
    rdq[i] = uscale[512 + c]  * (1.f/889.f);
    hdq[i] = uscale[1024 + c] * (1.f/889.f);
  }
  if (tid < 16) wmax[tid] = (t0 == 0) ? 1e-20f : sbuf[blockIdx.x];

  if (t0 == 0) {
    for (int i = tid; i < 16*512; i += 1024) hm[i>>9][i&511] = 0.f;
  } else {
    for (int i = tid; i < 16*512; i += 1024)
      hm[i>>9][i&511] = h_st[(size_t)(r0 + (i>>9))*HH + (i&511)];
  }
  asm volatile("s_waitcnt vmcnt(0)" ::: "memory");  // hm loads fully done
  __builtin_amdgcn_sched_barrier(0);

  // prologue staging: HG(step 0) [2 glds], B0, B1 [1 glds each]
  STAGEHG(PRE + (size_t)r0*TC*NN);
  STAGEB(0); STAGEB(1);

  u32x2 inZ[4][2];   // z/r depth-4 ring (2 tiles per slot)

  for (int tc = 0; tc < TC; ++tc) {
    const int bsv = bs[t0 + tc];
    if (bsv <= r0) break;                  // descending bs: done forever
    const int na = min(16, bsv - r0);
    const unsigned short* PREstep = PRE + ((size_t)r0*TC + tc)*NN;
    const unsigned short* PREnext = PREstep + NN;

    barrier_lds();                         // S1: prev hm + wmax writes visible
    asm volatile("s_waitcnt vmcnt(2)" ::: "memory");  // HG landed; B0,B1 fly
    __builtin_amdgcn_sched_barrier(0);

    // dynamic quant scale for hd (exact bound: |hd| <= max|h| = s)
    float s = wmax[0];
#pragma unroll
    for (int i = 1; i < 16; ++i) s = fmaxf(s, wmax[i]);
    const float qs = 127.f / s;

    // pz/pr clump (VGPR loads, consumed in epilogue A)
    unsigned short pzr[2][2][4];
#pragma unroll
    for (int i = 0; i < 2; ++i)
#pragma unroll
      for (int q = 0; q < 4; ++q) {
        int row = lg*4 + q, col = (w*2 + i)*16 + lr;
        const unsigned short* pb = PREstep + (size_t)row*rowStr + col;
        pzr[0][i][q] = pb[0];
        pzr[1][i][q] = pb[512];
      }

    // prefetch z/r units 0..3 into ring
    LOADZR(0, inZ[0]); LOADZR(1, inZ[1]);
    LOADZR(2, inZ[2]); LOADZR(3, inZ[3]);

    // hd build (waves 0..7, kt=w): quantize (act? gamma*h : h) + rowsum
    i32x4 qwReg;
    if (w < 8) {
      const int k0 = w*64 + lg*16;
      const bool act = lr < na;
      bf16x8 g0 = *(const bf16x8*)&slabHG[hgIdx(lr, 512 + k0)];
      bf16x8 g1 = *(const bf16x8*)&slabHG[hgIdx(lr, 512 + k0 + 8)];
      int psum = 0;
#pragma unroll
      for (int d = 0; d < 4; ++d) {
        int word = 0;
#pragma unroll
        for (int b = 0; b < 4; ++b) {
          int j = d*4 + b;
          float h  = hm[lr][k0 + j];
          float gv = bf2f((unsigned short)(j < 8 ? g0[j] : g1[j-8]));
          float hd = act ? gv*h : h;
          int qi = (int)rintf(hd*qs);
          psum += qi;
          word |= (qi & 0xFF) << (8*b);
        }
        qwReg[d] = word;
      }
      hd_l[w*64 + l] = qwReg;
      psum += __shfl_xor(psum, 16);
      psum += __shfl_xor(psum, 32);
      if (lg == 0) hsumW[w][lr] = psum;    // wave w's k-range [64w, 64w+64)
    }

    // hoist htilde-preact + gamma for my output cells (before r overwrites)
    float phv[2][4], ggv[2][4];
#pragma unroll
    for (int i = 0; i < 2; ++i)
#pragma unroll
      for (int q = 0; q < 4; ++q) {
        int row = lg*4 + q, col = (w*2 + i)*16 + lr;
        phv[i][q] = bf2f(slabHG[hgIdx(row, col)]);
        ggv[i][q] = bf2f(slabHG[hgIdx(row, 512 + col)]);
      }
    barrier_lds();                         // S2: hd_l + hsumW ready

    // ---- phase A: z|r, 16 units, depth-4 register ring ----
    i32x4 acc[4];
#pragma unroll
    for (int i = 0; i < 4; ++i) acc[i] = (i32x4){0, 0, 0, 0};
    i32x4 af;
#pragma unroll
    for (int u = 0; u < 16; ++u) {
      if (!(u & 1)) af = hd_l[(u>>1)*64 + l];
      __builtin_amdgcn_s_setprio(1);
#pragma unroll
      for (int i = 0; i < 2; ++i) {
        unsigned int W0 = inZ[u & 3][i][0], W1 = inZ[u & 3][i][1];
        i32x4 bfr;
        bfr[0] = (int)(W0 & 0x0F0F0F0Fu);
        bfr[1] = (int)((W0 >> 4) & 0x0F0F0F0Fu);
        bfr[2] = (int)(W1 & 0x0F0F0F0Fu);
        bfr[3] = (int)((W1 >> 4) & 0x0F0F0F0Fu);
        acc[(u&1)*2 + i] = __builtin_amdgcn_mfma_i32_16x16x64_i8(af, bfr, acc[(u&1)*2 + i], 0, 0, 0);
      }
      __builtin_amdgcn_s_setprio(0);
      if (u < 12) LOADZR(u + 4, inZ[u & 3]);
    }
    // stage Uh units 2,3 (covered by epilogue A + a2 build)
    STAGEB(2); STAGEB(3);

    // epilogue A: offset-correct, z -> regs; r -> slabHG (cols 0..511)
    int rsum[4];
#pragma unroll
    for (int q = 0; q < 4; ++q) {
      int row = lg*4 + q, t = 0;
#pragma unroll
      for (int w2 = 0; w2 < 8; ++w2) t += hsumW[w2][row];
      rsum[q] = t * 8;
    }
    float zreg[2][4];
#pragma unroll
    for (int i = 0; i < 2; ++i)
#pragma unroll
      for (int q = 0; q < 4; ++q) {
        int row = lg*4 + q, col = (w*2 + i)*16 + lr;
        float az = bf2f(pzr[0][i][q]) + (float)(acc[i][q]   - rsum[q]) * zdq[i] * s;
        float ar = bf2f(pzr[1][i][q]) + (float)(acc[2+i][q] - rsum[q]) * rdq[i] * s;
        zreg[i][q] = 1.f/(1.f + __expf(-az));
        slabHG[hgIdx(row, col)] = f2bf(1.f/(1.f + __expf(-ar)));
      }
    barrier_lds();                         // S3: r ready; phase-A hd_l reads done

    // a2 = hd*r quantized (waves 0..7; |hd_q*r| <= 127) + rowsum
    if (w < 8) {
      const int k0 = w*64 + lg*16;
      bf16x8 r0v = *(const bf16x8*)&slabHG[hgIdx(lr, k0)];
      bf16x8 r1v = *(const bf16x8*)&slabHG[hgIdx(lr, k0 + 8)];
      i32x4 nw;
      int psum2 = 0;
#pragma unroll
      for (int d = 0; d < 4; ++d) {
        int word = qwReg[d], out = 0;
#pragma unroll
        for (int b = 0; b < 4; ++b) {
          int j = d*4 + b;
          int hq = (int)(signed char)((word >> (8*b)) & 0xFF);
          float rv = bf2f((unsigned short)(j < 8 ? r0v[j] : r1v[j-8]));
          int qi = (int)rintf((float)hq * rv);
          psum2 += qi;
          out |= (qi & 0xFF) << (8*b);
        }
        nw[d] = out;
      }
      hd_l[w*64 + l] = nw;
      psum2 += __shfl_xor(psum2, 16);
      psum2 += __shfl_xor(psum2, 32);
      if (lg == 0) hsumW2[w][lr] = psum2;
    }
    barrier_lds();                         // S4: a2 frags + hsumW2 ready

    // ---- phase B: htilde, 8 units, depth-4 glds slots, counted vmcnt ----
    i32x4 accB[2];
#pragma unroll
    for (int i = 0; i < 2; ++i) accB[i] = (i32x4){0, 0, 0, 0};
#pragma unroll
    for (int u = 0; u < 8; ++u) {
      if (u < 5) { asm volatile("s_waitcnt vmcnt(3)" ::: "memory"); }
      else       { asm volatile("s_waitcnt vmcnt(4)" ::: "memory"); }
      __builtin_amdgcn_sched_barrier(0);
      const char* buf = &Ubuf[w][u & 3][0];
      i32x4 af2 = hd_l[u*64 + l];
      __builtin_amdgcn_s_setprio(1);
#pragma unroll
      for (int i = 0; i < 2; ++i) {
        u32x2 Wv = *(const u32x2*)&buf[i*512 + l*8];
        unsigned int W0 = Wv[0], W1 = Wv[1];
        i32x4 bfr;
        bfr[0] = (int)(W0 & 0x0F0F0F0Fu);
        bfr[1] = (int)((W0 >> 4) & 0x0F0F0F0Fu);
        bfr[2] = (int)(W1 & 0x0F0F0F0Fu);
        bfr[3] = (int)((W1 >> 4) & 0x0F0F0F0Fu);
        accB[i] = __builtin_amdgcn_mfma_i32_16x16x64_i8(af2, bfr, accB[i], 0, 0, 0);
      }
      __builtin_amdgcn_s_setprio(0);
      __builtin_amdgcn_sched_barrier(0);
      if (u < 4)       STAGEB(u + 4);      // B4..B7 -> slots 0..3 (just freed)
      else if (u == 4) STAGEHG(PREnext);
      else if (u == 5) STAGEB(0);          // next step's B0
      else if (u == 6) STAGEB(1);          // next step's B1
    }

    // epilogue B: h update + block max|h| for next step's quant scale
    int rsum2[4];
#pragma unroll
    for (int q = 0; q < 4; ++q) {
      int row = lg*4 + q, t = 0;
#pragma unroll
      for (int w2 = 0; w2 < 8; ++w2) t += hsumW2[w2][row];
      rsum2[q] = t * 8;
    }
    float mloc = 0.f;
#pragma unroll
    for (int i = 0; i < 2; ++i)
#pragma unroll
      for (int q = 0; q < 4; ++q) {
        int row = lg*4 + q, col = (w*2 + i)*16 + lr;
        float hval;
        if (row < na) {
          float ah = phv[i][q] + (float)(accB[i][q] - rsum2[q]) * hdq[i] * s;
          float e  = __expf(2.f*ah);
          float th = 1.f - 2.f/(e + 1.f);          // tanh, overflow-safe
          float hd = ggv[i][q] * hm[row][col];
          hval = hd + zreg[i][q]*(th - hd);
          hm[row][col] = hval;
        } else {
          hval = hm[row][col];
        }
        mloc = fmaxf(mloc, fabsf(hval));
      }
#pragma unroll
    for (int off = 32; off > 0; off >>= 1) mloc = fmaxf(mloc, __shfl_xor(mloc, off));
    if (l == 0) wmax[w] = fmaxf(mloc, 1e-20f);
  }

  asm volatile("s_waitcnt vmcnt(0)" ::: "memory");  // drain stray prefetches
  barrier_lds();
  for (int i = tid; i < 16*512; i += 1024)
    h_st[(size_t)(r0 + (i>>9))*HH + (i&511)] = hm[i>>9][i&511];
  if (tid == 0) {
    float s = wmax[0];
#pragma unroll
    for (int i = 1; i < 16; ++i) s = fmaxf(s, wmax[i]);
    sbuf[blockIdx.x] = s;
  }
}

// ---------------------------------------------------------------------------
// K4: head: eval BatchNorm + decoder GEMV + log_softmax.
//   d_out = [output (256x64) | h_bn (256x512)] fp32
// ---------------------------------------------------------------------------
__global__ __launch_bounds__(64) void head_kernel(
    const float* __restrict__ h_state, const float* __restrict__ decW,
    const float* __restrict__ decb, const float* __restrict__ bnw,
    const float* __restrict__ bnb, float* __restrict__ out)
{
  int b = blockIdx.x, o = threadIdx.x;
  __shared__ float hbn[HH];
  const float s = rsqrtf(1.f + 1e-5f);
  for (int j = o; j < HH; j += 64)
    hbn[j] = h_state[(long)b*HH + j] * (bnw[j] * s) + bnb[j];
  __syncthreads();
  float acc = decb[o];
  for (int j = 0; j < HH; ++j) acc += hbn[j] * decW[j*OO + o];
  float mx = acc;
#pragma unroll
  for (int off = 32; off > 0; off >>= 1) mx = fmaxf(mx, __shfl_xor(mx, off));
  float ex = __expf(acc - mx);
  float sum = ex;
#pragma unroll
  for (int off = 32; off > 0; off >>= 1) sum += __shfl_xor(sum, off);
  out[(long)b*OO + o] = acc - mx - __logf(sum);
  for (int j = o; j < HH; j += 64)
    out[(long)BB*OO + (long)b*HH + j] = hbn[j];
}

// ---------------------------------------------------------------------------
extern "C" void kernel_launch(void* const* d_in, const int* in_sizes, int n_in,
                              void* d_out, int out_size, void* d_ws, size_t ws_size,
                              hipStream_t stream) {
  const float* x     = (const float*)d_in[0];
  const float* delta = (const float*)d_in[1];
  const float* mm    = (const float*)d_in[2];
  const float* xf    = (const float*)d_in[3];
  const int*   bs    = (const int*)  d_in[4];
  const float* W_r   = (const float*)d_in[5];
  const float* U_r   = (const float*)d_in[6];
  const float* V_r   = (const float*)d_in[7];
  const float* b_r   = (const float*)d_in[8];
  const float* W_z   = (const float*)d_in[9];
  const float* U_z   = (const float*)d_in[10];
  const float* V_z   = (const float*)d_in[11];
  const float* b_z   = (const float*)d_in[12];
  const float* W     = (const float*)d_in[13];
  const float* U     = (const float*)d_in[14];
  const float* V     = (const float*)d_in[15];
  const float* b     = (const float*)d_in[16];
  const float* Wgx   = (const float*)d_in[17];
  const float* bgx   = (const float*)d_in[18];
  const float* Wgh   = (const float*)d_in[19];
  const float* bgh   = (const float*)d_in[20];
  const float* decW  = (const float*)d_in[21];
  const float* decb  = (const float*)d_in[22];
  const float* bnw   = (const float*)d_in[23];
  const float* bnb   = (const float*)d_in[24];

  auto rnd = [](size_t v) { return (v + 255) & ~(size_t)255; };
  const size_t fixed_bytes = rnd((size_t)2048*256*2) + rnd(2048*4)
                           + rnd((size_t)256*1024) + rnd((size_t)128*1024)
                           + rnd(1536*4) + rnd(64)
                           + rnd((size_t)BB*HH*4);
  int TC = 0;
  const int cands[5] = {128, 64, 32, 16, 8};
  for (int i = 0; i < 5; ++i) {
    size_t need = fixed_bytes + rnd((size_t)BB*cands[i]*KK*2) + rnd((size_t)BB*cands[i]*NN*2);
    if (need <= ws_size) { TC = cands[i]; break; }
  }
  if (TC == 0) return;

  char* p = (char*)d_ws;
  auto alloc = [&](size_t bytes) { char* r = p; p += (bytes + 255) & ~(size_t)255; return r; };
  unsigned short* A_chunk = (unsigned short*)alloc((size_t)BB * TC * KK * 2);
  unsigned short* PREc    = (unsigned short*)alloc((size_t)BB * TC * NN * 2);
  unsigned short* BwT     = (unsigned short*)alloc((size_t)2048 * 256 * 2);
  float*          bias    = (float*)alloc(2048 * 4);
  unsigned int*   UzrN    = (unsigned int*)alloc((size_t)256 * 1024);
  unsigned int*   UhN     = (unsigned int*)alloc((size_t)128 * 1024);
  float*          uscale  = (float*)alloc(1536 * 4);
  float*          sbuf    = (float*)alloc(64);
  float*          h_st    = (float*)alloc((size_t)BB * HH * 4);

  prep_scales_kernel<<<6, 256, 0, stream>>>(U_z, U_r, U, uscale);
  prep_kernel<<<2440, 256, 0, stream>>>(W_z, V_z, b_z, W_r, V_r, b_r, W, V, b,
                                        Wgh, bgh, U_z, U_r, U, uscale,
                                        BwT, bias, UzrN, UhN);
  const int nch = TT / TC;
  for (int c = 0; c < nch; ++c) {
    int t0 = c * TC;
    build_A_kernel<<<BB*TC/8, 256, 0, stream>>>(x, delta, mm, xf, Wgx, bgx, bs,
                                                A_chunk, t0, TC);
    gemm1_kernel<<<(BB*TC/128)*16, 256, 0, stream>>>(A_chunk, BwT, bias, bs,
                                                     PREc, t0, TC);
    scan_kernel<<<16, 1024, 0, stream>>>(PREc, UzrN, UhN, uscale, bs,
                                         h_st, sbuf, t0, TC);
  }
  head_kernel<<<256, 64, 0, stream>>>(h_st, decW, decb, bnw, bnb, (float*)d_out);
}

// Round 14
// 22814.168 us; speedup vs baseline: 1.1002x; 1.0161x over previous
//
#include <hip/hip_runtime.h>
#include <hip/hip_bf16.h>

typedef __attribute__((ext_vector_type(8))) short bf16x8;
typedef __attribute__((ext_vector_type(4))) float f32x4;
typedef __attribute__((ext_vector_type(4))) float fvec4;
typedef __attribute__((ext_vector_type(4))) unsigned short u16x4;
typedef __attribute__((ext_vector_type(4))) int i32x4;
typedef __attribute__((ext_vector_type(2))) unsigned int u32x2;

#define DEVI __device__ __forceinline__

constexpr int BB = 256, TT = 1024, FF = 128, HH = 512, OO = 64;
constexpr int KK = 256;    // fused input width [x_imp | m]
constexpr int NN = 2048;   // fused gate width  [z | r | htilde | gamma_h]

DEVI unsigned short f2bf(float x) {
  unsigned int u = __float_as_uint(x);
  u += 0x7FFFu + ((u >> 16) & 1u);          // RNE
  return (unsigned short)(u >> 16);
}
DEVI float bf2f(unsigned short s) {
  return __uint_as_float(((unsigned int)s) << 16);
}

DEVI void gload16(const void* g, void* lds) {
  __builtin_amdgcn_global_load_lds(
      (const __attribute__((address_space(1))) void*)g,
      (__attribute__((address_space(3))) void*)lds, 16, 0, 0);
}

DEVI void barrier_lds() {       // raw barrier: waits LDS ops only, vmcnt SURVIVES
  asm volatile("s_waitcnt lgkmcnt(0)" ::: "memory");
  __builtin_amdgcn_s_barrier();
  __builtin_amdgcn_sched_barrier(0);
}

// slabHG address swizzle (shorts): involution within a row, applied on BOTH
// the stage source and every read/write.
DEVI int hgIdx(int row, int c) { return row*1024 + (c ^ ((row & 7) << 3)); }

// ---------------------------------------------------------------------------
// K0a: per-column scales s_n = max_k |U[k][n]|  (z:0..511, r:512..1023, h:1024..1535)
// ---------------------------------------------------------------------------
__global__ __launch_bounds__(256) void prep_scales_kernel(
    const float* __restrict__ U_z, const float* __restrict__ U_r,
    const float* __restrict__ Uh, float* __restrict__ uscale)
{
  int n = blockIdx.x * 256 + threadIdx.x;
  if (n >= 1536) return;
  const float* src = (n < 512) ? U_z : (n < 1024) ? U_r : Uh;
  int col = n & 511;
  float s = 0.f;
  for (int k = 0; k < HH; ++k) s = fmaxf(s, fabsf(src[k*HH + col]));
  uscale[n] = fmaxf(s, 1e-30f);
}

// ---------------------------------------------------------------------------
// K0b: pack weights.
//   BwT [2048][256] bf16, bias[2048] f32 (as before)
//   UzrN u4 [16 u][8 wv][4 i][64 l][2 c] words (unit u = kt*2+half; half0=Uz)
//   UhN  u4 [ 8 u][8 wv][4 i][64 l][2 c] words (unit u = kt)
//   Word (…,c): nibble p = value q+8 at j = c*8 + (p&1)*4 + (p>>1),
//   k = base_k + (l>>4)*16 + j, col = (wv*4+i)*16 + (l&15),
//   q = clamp(round(U/s_col*7), -7, 7). Unpack = W&0x0F0F0F0F / (W>>4)&…
// ---------------------------------------------------------------------------
__global__ __launch_bounds__(256) void prep_kernel(
    const float* __restrict__ W_z, const float* __restrict__ V_z, const float* __restrict__ b_z,
    const float* __restrict__ W_r, const float* __restrict__ V_r, const float* __restrict__ b_r,
    const float* __restrict__ Wh,  const float* __restrict__ Vh,  const float* __restrict__ bh,
    const float* __restrict__ Wgh, const float* __restrict__ bgh,
    const float* __restrict__ U_z, const float* __restrict__ U_r, const float* __restrict__ Uh,
    const float* __restrict__ uscale,
    unsigned short* __restrict__ BwT, float* __restrict__ bias,
    unsigned int* __restrict__ UzrN, unsigned int* __restrict__ UhN)
{
  int idx = blockIdx.x * 256 + threadIdx.x;
  if (idx < 524288) {                       // BwT
    int n = idx >> 8, k = idx & 255;
    float v;
    if (n < 512)       { int h = n;        v = (k < 128) ? W_z[k*HH + h] : -V_z[(k-128)*HH + h]; }
    else if (n < 1024) { int h = n - 512;  v = (k < 128) ? W_r[k*HH + h] : -V_r[(k-128)*HH + h]; }
    else if (n < 1536) { int h = n - 1024; v = (k < 128) ? Wh [k*HH + h] : -Vh [(k-128)*HH + h]; }
    else               { int h = n - 1536; v = (k < 128) ? 0.f : Wgh[(k-128)*HH + h]; }
    BwT[n*256 + k] = f2bf(v);
    return;
  }
  idx -= 524288;
  if (idx < 2048) {                         // bias
    int n = idx; float v;
    if (n < 512)       { float s = b_z[n];      for (int f = 0; f < FF; ++f) s += V_z[f*HH + n];        v = s; }
    else if (n < 1024) { int h = n-512;  float s = b_r[h]; for (int f = 0; f < FF; ++f) s += V_r[f*HH + h]; v = s; }
    else if (n < 1536) { int h = n-1024; float s = bh[h];  for (int f = 0; f < FF; ++f) s += Vh[f*HH + h];  v = s; }
    else               { v = bgh[n-1536]; }
    bias[n] = v;
    return;
  }
  idx -= 2048;
  if (idx < 65536) {                        // UzrN words (i4, permuted, +8)
    int c  = idx & 1;
    int l  = (idx >> 1) & 63;
    int i  = (idx >> 7) & 3;
    int wv = (idx >> 9) & 7;
    int u  = idx >> 12;                    // 0..15
    int kt = u >> 1, half = u & 1;
    int col = (wv*4 + i)*16 + (l & 15);
    const float* src = half ? U_r : U_z;
    float sc = 7.f / uscale[half*512 + col];
    unsigned int word = 0;
#pragma unroll
    for (int p = 0; p < 8; ++p) {
      int j = c*8 + (p & 1)*4 + (p >> 1);
      int k = kt*64 + (l >> 4)*16 + j;
      float q = fminf(fmaxf(rintf(src[k*HH + col] * sc), -7.f), 7.f);
      unsigned int uq = (unsigned int)((int)q + 8);
      word |= (uq & 0xF) << (4*p);
    }
    UzrN[idx] = word;
    return;
  }
  idx -= 65536;
  if (idx < 32768) {                        // UhN words (i4, permuted, +8)
    int c  = idx & 1;
    int l  = (idx >> 1) & 63;
    int i  = (idx >> 7) & 3;
    int wv = (idx >> 9) & 7;
    int u  = idx >> 12;                    // 0..7 (kt)
    int col = (wv*4 + i)*16 + (l & 15);
    float sc = 7.f / uscale[1024 + col];
    unsigned int word = 0;
#pragma unroll
    for (int p = 0; p < 8; ++p) {
      int j = c*8 + (p & 1)*4 + (p >> 1);
      int k = u*64 + (l >> 4)*16 + j;
      float q = fminf(fmaxf(rintf(Uh[k*HH + col] * sc), -7.f), 7.f);
      unsigned int uq = (unsigned int)((int)q + 8);
      word |= (uq & 0xF) << (4*p);
    }
    UhN[idx] = word;
  }
}

// ---------------------------------------------------------------------------
// K1: imputation + fused A chunk [B*TC][256] bf16 = [x_imp | m]
// ---------------------------------------------------------------------------
__global__ __launch_bounds__(256) void build_A_kernel(
    const float* __restrict__ x, const float* __restrict__ delta,
    const float* __restrict__ mm, const float* __restrict__ xf,
    const float* __restrict__ Wgx, const float* __restrict__ bgx,
    const int* __restrict__ bs, unsigned short* __restrict__ A,
    int t0, int TC)
{
  int blk = blockIdx.x;
  int row8 = blk * 8;
  int b0  = row8 / TC;
  int tl0 = row8 % TC;
  if (b0 >= bs[t0 + tl0]) return;
  int tid = threadIdx.x;
  int rl = row8 + (tid >> 5);
  int tc = tl0 + (tid >> 5);
  long gi = ((long)b0*TT + t0 + tc) * 32 + (tid & 31);
  int f0 = (tid & 31) * 4;
  fvec4 xv = ((const fvec4*)x)[gi];
  fvec4 dv = ((const fvec4*)delta)[gi];
  fvec4 mv = ((const fvec4*)mm)[gi];
  fvec4 fv = ((const fvec4*)xf)[gi];
  unsigned short ox[4], om[4];
#pragma unroll
  for (int j = 0; j < 4; ++j) {
    float g  = __expf(-fmaxf(dv[j]*Wgx[f0+j] + bgx[f0+j], 0.f));
    float xr = g*fv[j] + (1.f - g)*0.001f;
    float xi = (mv[j] > 0.5f) ? xr : xv[j];
    ox[j] = f2bf(xi); om[j] = f2bf(mv[j]);
  }
  *(u16x4*)(A + (long)rl*KK + f0)       = (u16x4){ox[0], ox[1], ox[2], ox[3]};
  *(u16x4*)(A + (long)rl*KK + 128 + f0) = (u16x4){om[0], om[1], om[2], om[3]};
}

// ---------------------------------------------------------------------------
// K2: chunk GEMM  PRE[m][n] = A[m][:] @ Bw[:,n] + bias[n]  (bf16 MFMA, K=256)
// ---------------------------------------------------------------------------
__global__ __launch_bounds__(256) void gemm1_kernel(
    const unsigned short* __restrict__ A, const unsigned short* __restrict__ BwT,
    const float* __restrict__ bias, const int* __restrict__ bs,
    unsigned short* __restrict__ PRE, int t0, int TC)
{
  int blk = blockIdx.x;
  int nt = blk & 15;
  int mt = blk >> 4;
  {
    int m0 = mt * 128;
    int b_ = m0 / TC;
    int bcheck = (TC >= 128) ? bs[t0 + (m0 % TC)] : bs[t0];
    if (b_ >= bcheck) return;
  }
  int tid = threadIdx.x;
  int w = tid >> 6, l = tid & 63;
  int wm = w >> 1, wn = w & 1;
  int lr = l & 15, lg = l >> 4;
  int m_base = mt*128 + wm*64;
  int n_base = nt*128 + wn*64;
  const unsigned short* Aptr = A   + (long)(m_base + lr)*KK + lg*8;
  const unsigned short* Bptr = BwT + (long)(n_base + lr)*KK + lg*8;
  f32x4 acc[4][4];
#pragma unroll
  for (int i = 0; i < 4; ++i)
#pragma unroll
    for (int j = 0; j < 4; ++j) acc[i][j] = (f32x4){0.f, 0.f, 0.f, 0.f};

#pragma unroll
  for (int kt = 0; kt < 8; ++kt) {
    bf16x8 af[4], bfr[4];
#pragma unroll
    for (int i = 0; i < 4; ++i) af[i]  = *(const bf16x8*)(Aptr + (long)i*16*KK + kt*32);
#pragma unroll
    for (int i = 0; i < 4; ++i) bfr[i] = *(const bf16x8*)(Bptr + (long)i*16*KK + kt*32);
#pragma unroll
    for (int ms = 0; ms < 4; ++ms)
#pragma unroll
      for (int ns = 0; ns < 4; ++ns)
        acc[ms][ns] = __builtin_amdgcn_mfma_f32_16x16x32_bf16(af[ms], bfr[ns], acc[ms][ns], 0, 0, 0);
  }
#pragma unroll
  for (int ms = 0; ms < 4; ++ms) {
    int gm0 = m_base + ms*16 + lg*4;
#pragma unroll
    for (int ns = 0; ns < 4; ++ns) {
      int gn = n_base + ns*16 + lr;
      float bv = bias[gn];
      bool is_gamma = (gn >= 1536);
#pragma unroll
      for (int q = 0; q < 4; ++q) {
        float v = acc[ms][ns][q] + bv;
        if (is_gamma) v = __expf(-fmaxf(v, 0.f));
        PRE[(long)(gm0 + q)*NN + gn] = f2bf(v);
      }
    }
  }
}

// ---------------------------------------------------------------------------
// K3: sequential scan, 16 blocks x 512 threads (8 waves), i8 MFMA (K=64).
//   r11 structure, serial chain shortened to 3 barriers/step:
//     S1 (vmcnt(20) for HG, before s_barrier), S2 (hd_l), S4 (a2_l + slab).
//   S3 removed: epilogue-A r cols [64w,64w+64) are written AND read by wave
//   w only (same-wave lgkmcnt ordering); a2 goes to separate a2_l buffer so
//   phase-A hd_l readers are never overwritten. zr ring prefetch for step
//   t+1 issued at phase-B tail (registers survive barriers; U invariant).
// ---------------------------------------------------------------------------
__global__ __launch_bounds__(512, 2) void scan_kernel(
    const unsigned short* __restrict__ PRE,
    const unsigned int* __restrict__ UzrN,
    const unsigned int* __restrict__ UhN,
    const float* __restrict__ uscale,
    const int* __restrict__ bs,
    float* __restrict__ h_st,
    float* __restrict__ sbuf,
    int t0, int TC)
{
  __shared__ __align__(16) char Ubuf[8][4][2048];          // 64 KB (4-slot Uh dbuf)
  __shared__ __align__(16) i32x4 hd_l[8*64];               // 8 KB hd frags
  __shared__ __align__(16) i32x4 a2_l[8*64];               // 8 KB a2 frags
  __shared__ __align__(16) unsigned short slabHG[16*1024]; // 32 KB [row][htld|r : gamma]
  __shared__ float hm[16][524];                            // 33.5 KB h master
  __shared__ int hsumW[8][16];                             // hd rowsum partials
  __shared__ int hsumW2[8][16];                            // a2 rowsum partials
  __shared__ float wmax[8];

  const int tid = threadIdx.x;
  const int r0 = blockIdx.x * 16;
  if (t0 > 0 && bs[t0] <= r0) return;

  const int w = tid >> 6, l = tid & 63, lr = l & 15, lg = l >> 4;
  const size_t rowStr = (size_t)TC * NN;

  auto STAGEB = [&](int u) {   // Uh unit u (2 KB): 2 glds of 16B/lane
    const char* src = (const char*)UhN + ((size_t)(u*8 + w))*2048 + (size_t)l*16;
    char* dst = &Ubuf[w][u & 3][0];
    gload16(src, dst);
    gload16(src + 1024, dst + 1024);
  };
  auto STAGEHG = [&](const unsigned short* PREn) {  // htilde+gamma halves, swizzled source
#pragma unroll
    for (int j = 0; j < 4; ++j) {
      int idx = w*4 + j;
      int row = idx >> 1;
      int phys = (idx & 1)*512 + l*8;
      int logi = phys ^ ((row & 7) << 3);
      const unsigned short* src = PREn + (size_t)row*rowStr + 1024 + logi;
      gload16(src, &slabHG[idx*512]);
    }
  };
  auto LOADZR = [&](int u, u32x2* d) {   // z/r unit u: 4 tiles x 8B per thread
#pragma unroll
    for (int i = 0; i < 4; ++i)
      d[i] = ((const u32x2*)UzrN)[(u*8 + w)*256 + i*64 + l];
  };

  // per-thread dequant constants
  float zdq[4], rdq[4], hdq[4];
#pragma unroll
  for (int i = 0; i < 4; ++i) {
    int c = (w*4 + i)*16 + lr;
    zdq[i] = uscale[c]        * (1.f/889.f);    // 7 * 127
    rdq[i] = uscale[512 + c]  * (1.f/889.f);
    hdq[i] = uscale[1024 + c] * (1.f/889.f);
  }
  if (tid < 8) wmax[tid] = (t0 == 0) ? 1e-20f : sbuf[blockIdx.x];

  if (t0 == 0) {
    for (int i = tid; i < 16*512; i += 512) hm[i>>9][i&511] = 0.f;
  } else {
    for (int i = tid; i < 16*512; i += 512)
      hm[i>>9][i&511] = h_st[(size_t)(r0 + (i>>9))*HH + (i&511)];
  }
  asm volatile("s_waitcnt vmcnt(0)" ::: "memory");  // hm loads fully done
  __builtin_amdgcn_sched_barrier(0);

  // prologue staging: HG(step 0) [4], B0 [2], B1 [2], zr ring 0..3 [16]
  u32x2 inZ[4][4];
  STAGEHG(PRE + (size_t)r0*TC*NN);
  STAGEB(0); STAGEB(1);
  __builtin_amdgcn_sched_barrier(0);
  LOADZR(0, inZ[0]); LOADZR(1, inZ[1]);
  LOADZR(2, inZ[2]); LOADZR(3, inZ[3]);

  for (int tc = 0; tc < TC; ++tc) {
    const int bsv = bs[t0 + tc];
    if (bsv <= r0) break;                  // descending bs: done forever
    const int na = min(16, bsv - r0);
    const unsigned short* PREstep = PRE + ((size_t)r0*TC + tc)*NN;
    const unsigned short* PREnext = PREstep + NN;

    // S1: HG landed (vmcnt BEFORE barrier for cross-wave glds visibility);
    // FIFO at entry: [HG 4][B0 2][B1 2][ZR 16] -> newer-than-HG = 20.
    asm volatile("s_waitcnt lgkmcnt(0)" ::: "memory");
    asm volatile("s_waitcnt vmcnt(20)" ::: "memory");
    __builtin_amdgcn_s_barrier();
    __builtin_amdgcn_sched_barrier(0);

    // dynamic quant scale for hd (exact bound: |hd| <= max|h| = s)
    float s = wmax[0];
#pragma unroll
    for (int i = 1; i < 8; ++i) s = fmaxf(s, wmax[i]);
    const float qs = 127.f / s;

    // pz/pr clump (VGPR loads, consumed in epilogue A)
    unsigned short pzr[2][4][4];
#pragma unroll
    for (int i = 0; i < 4; ++i)
#pragma unroll
      for (int q = 0; q < 4; ++q) {
        int row = lg*4 + q, col = (w*4 + i)*16 + lr;
        const unsigned short* pb = PREstep + (size_t)row*rowStr + col;
        pzr[0][i][q] = pb[0];
        pzr[1][i][q] = pb[512];
      }

    // hd build (kt = w): quantize (act? gamma*h : h) to i8 frags + rowsum
    i32x4 qwReg;
    {
      const int k0 = w*64 + lg*16;
      const bool act = lr < na;
      bf16x8 g0 = *(const bf16x8*)&slabHG[hgIdx(lr, 512 + k0)];
      bf16x8 g1 = *(const bf16x8*)&slabHG[hgIdx(lr, 512 + k0 + 8)];
      int psum = 0;
#pragma unroll
      for (int d = 0; d < 4; ++d) {
        int word = 0;
#pragma unroll
        for (int b = 0; b < 4; ++b) {
          int j = d*4 + b;
          float h  = hm[lr][k0 + j];
          float gv = bf2f((unsigned short)(j < 8 ? g0[j] : g1[j-8]));
          float hd = act ? gv*h : h;
          int qi = (int)rintf(hd*qs);
          psum += qi;
          word |= (qi & 0xFF) << (8*b);
        }
        qwReg[d] = word;
      }
      hd_l[w*64 + l] = qwReg;
      psum += __shfl_xor(psum, 16);
      psum += __shfl_xor(psum, 32);
      if (lg == 0) hsumW[w][lr] = psum;    // wave w's k-range [64w, 64w+64)
    }

    // hoist htilde-preact + gamma (slab r-region overwritten in epilogue A,
    // full slab overwritten by next-step staging at phase-B u==4)
    float phv[4][4], ggv[4][4];
#pragma unroll
    for (int i = 0; i < 4; ++i)
#pragma unroll
      for (int q = 0; q < 4; ++q) {
        int row = lg*4 + q, col = (w*4 + i)*16 + lr;
        phv[i][q] = bf2f(slabHG[hgIdx(row, col)]);
        ggv[i][q] = bf2f(slabHG[hgIdx(row, 512 + col)]);
      }
    barrier_lds();                         // S2: hd_l + hsumW ready

    // ---- phase A: z|r, 16 units, depth-4 register ring ----
    i32x4 acc[8];
#pragma unroll
    for (int i = 0; i < 8; ++i) acc[i] = (i32x4){0, 0, 0, 0};
    i32x4 af;
#pragma unroll
    for (int u = 0; u < 16; ++u) {
      if (!(u & 1)) af = hd_l[(u>>1)*64 + l];
      __builtin_amdgcn_s_setprio(1);
#pragma unroll
      for (int i = 0; i < 4; ++i) {
        unsigned int W0 = inZ[u & 3][i][0], W1 = inZ[u & 3][i][1];
        i32x4 bfr;
        bfr[0] = (int)(W0 & 0x0F0F0F0Fu);
        bfr[1] = (int)((W0 >> 4) & 0x0F0F0F0Fu);
        bfr[2] = (int)(W1 & 0x0F0F0F0Fu);
        bfr[3] = (int)((W1 >> 4) & 0x0F0F0F0Fu);
        acc[(u&1)*4 + i] = __builtin_amdgcn_mfma_i32_16x16x64_i8(af, bfr, acc[(u&1)*4 + i], 0, 0, 0);
      }
      __builtin_amdgcn_s_setprio(0);
      if (u < 12) LOADZR(u + 4, inZ[u & 3]);
    }
    // stage Uh units 2,3 (covered by epilogue A + a2 build)
    STAGEB(2); STAGEB(3);

    // epilogue A: offset-correct, z -> regs; r -> slabHG (cols 0..511)
    int rsum[4];
#pragma unroll
    for (int q = 0; q < 4; ++q) {
      int row = lg*4 + q, t = 0;
#pragma unroll
      for (int w2 = 0; w2 < 8; ++w2) t += hsumW[w2][row];
      rsum[q] = t * 8;
    }
    float zreg[4][4];
#pragma unroll
    for (int i = 0; i < 4; ++i)
#pragma unroll
      for (int q = 0; q < 4; ++q) {
        int row = lg*4 + q, col = (w*4 + i)*16 + lr;
        float az = bf2f(pzr[0][i][q]) + (float)(acc[i][q]   - rsum[q]) * zdq[i] * s;
        float ar = bf2f(pzr[1][i][q]) + (float)(acc[4+i][q] - rsum[q]) * rdq[i] * s;
        zreg[i][q] = 1.f/(1.f + __expf(-az));
        slabHG[hgIdx(row, col)] = f2bf(1.f/(1.f + __expf(-ar)));
      }
    // same-wave r visibility (wave w wrote exactly the cols it now reads)
    asm volatile("s_waitcnt lgkmcnt(0)" ::: "memory");
    __builtin_amdgcn_sched_barrier(0);

    // a2 = hd*r quantized (register hd; |hd_q*r| <= 127) -> a2_l + rowsum
    {
      const int k0 = w*64 + lg*16;
      bf16x8 r0v = *(const bf16x8*)&slabHG[hgIdx(lr, k0)];
      bf16x8 r1v = *(const bf16x8*)&slabHG[hgIdx(lr, k0 + 8)];
      i32x4 nw;
      int psum2 = 0;
#pragma unroll
      for (int d = 0; d < 4; ++d) {
        int word = qwReg[d], out = 0;
#pragma unroll
        for (int b = 0; b < 4; ++b) {
          int j = d*4 + b;
          int hq = (int)(signed char)((word >> (8*b)) & 0xFF);
          float rv = bf2f((unsigned short)(j < 8 ? r0v[j] : r1v[j-8]));
          int qi = (int)rintf((float)hq * rv);
          psum2 += qi;
          out |= (qi & 0xFF) << (8*b);
        }
        nw[d] = out;
      }
      a2_l[w*64 + l] = nw;
      psum2 += __shfl_xor(psum2, 16);
      psum2 += __shfl_xor(psum2, 32);
      if (lg == 0) hsumW2[w][lr] = psum2;
    }
    barrier_lds();                         // S4: a2_l + hsumW2 ready; slab free

    // ---- phase B: htilde, 8 units, depth-4 glds slots, counted vmcnt ----
    i32x4 accB[4];
#pragma unroll
    for (int i = 0; i < 4; ++i) accB[i] = (i32x4){0, 0, 0, 0};
#pragma unroll
    for (int u = 0; u < 8; ++u) {
      if (u < 5) { asm volatile("s_waitcnt vmcnt(6)" ::: "memory"); }
      else       { asm volatile("s_waitcnt vmcnt(8)" ::: "memory"); }
      __builtin_amdgcn_sched_barrier(0);
      const char* buf = &Ubuf[w][u & 3][0];
      i32x4 af2 = a2_l[u*64 + l];
      __builtin_amdgcn_s_setprio(1);
#pragma unroll
      for (int i = 0; i < 4; ++i) {
        u32x2 Wv = *(const u32x2*)&buf[(i*64 + l)*8];
        unsigned int W0 = Wv[0], W1 = Wv[1];
        i32x4 bfr;
        bfr[0] = (int)(W0 & 0x0F0F0F0Fu);
        bfr[1] = (int)((W0 >> 4) & 0x0F0F0F0Fu);
        bfr[2] = (int)(W1 & 0x0F0F0F0Fu);
        bfr[3] = (int)((W1 >> 4) & 0x0F0F0F0Fu);
        accB[i] = __builtin_amdgcn_mfma_i32_16x16x64_i8(af2, bfr, accB[i], 0, 0, 0);
      }
      __builtin_amdgcn_s_setprio(0);
      __builtin_amdgcn_sched_barrier(0);
      if (u < 4)       STAGEB(u + 4);      // B4..B7 -> slots 0..3 (just freed)
      else if (u == 4) STAGEHG(PREnext);
      else if (u == 5) STAGEB(0);          // next step's B0
      else if (u == 6) STAGEB(1);          // next step's B1
    }
    // next step's zr ring (after the glds above -> S1 count stays provable)
    __builtin_amdgcn_sched_barrier(0);
    LOADZR(0, inZ[0]); LOADZR(1, inZ[1]);
    LOADZR(2, inZ[2]); LOADZR(3, inZ[3]);
    __builtin_amdgcn_sched_barrier(0);

    // epilogue B: h update + block max|h| for next step's quant scale
    int rsum2[4];
#pragma unroll
    for (int q = 0; q < 4; ++q) {
      int row = lg*4 + q, t = 0;
#pragma unroll
      for (int w2 = 0; w2 < 8; ++w2) t += hsumW2[w2][row];
      rsum2[q] = t * 8;
    }
    float mloc = 0.f;
#pragma unroll
    for (int i = 0; i < 4; ++i)
#pragma unroll
      for (int q = 0; q < 4; ++q) {
        int row = lg*4 + q, col = (w*4 + i)*16 + lr;
        float hval;
        if (row < na) {
          float ah = phv[i][q] + (float)(accB[i][q] - rsum2[q]) * hdq[i] * s;
          float e  = __expf(2.f*ah);
          float th = 1.f - 2.f/(e + 1.f);          // tanh, overflow-safe
          float hd = ggv[i][q] * hm[row][col];
          hval = hd + zreg[i][q]*(th - hd);
          hm[row][col] = hval;
        } else {
          hval = hm[row][col];
        }
        mloc = fmaxf(mloc, fabsf(hval));
      }
#pragma unroll
    for (int off = 32; off > 0; off >>= 1) mloc = fmaxf(mloc, __shfl_xor(mloc, off));
    if (l == 0) wmax[w] = fmaxf(mloc, 1e-20f);
  }

  asm volatile("s_waitcnt vmcnt(0)" ::: "memory");  // drain stray prefetches
  barrier_lds();
  for (int i = tid; i < 16*512; i += 512)
    h_st[(size_t)(r0 + (i>>9))*HH + (i&511)] = hm[i>>9][i&511];
  if (tid == 0) {
    float s = wmax[0];
#pragma unroll
    for (int i = 1; i < 8; ++i) s = fmaxf(s, wmax[i]);
    sbuf[blockIdx.x] = s;
  }
}

// ---------------------------------------------------------------------------
// K4: head: eval BatchNorm + decoder GEMV + log_softmax.
//   d_out = [output (256x64) | h_bn (256x512)] fp32
// ---------------------------------------------------------------------------
__global__ __launch_bounds__(64) void head_kernel(
    const float* __restrict__ h_state, const float* __restrict__ decW,
    const float* __restrict__ decb, const float* __restrict__ bnw,
    const float* __restrict__ bnb, float* __restrict__ out)
{
  int b = blockIdx.x, o = threadIdx.x;
  __shared__ float hbn[HH];
  const float s = rsqrtf(1.f + 1e-5f);
  for (int j = o; j < HH; j += 64)
    hbn[j] = h_state[(long)b*HH + j] * (bnw[j] * s) + bnb[j];
  __syncthreads();
  float acc = decb[o];
  for (int j = 0; j < HH; ++j) acc += hbn[j] * decW[j*OO + o];
  float mx = acc;
#pragma unroll
  for (int off = 32; off > 0; off >>= 1) mx = fmaxf(mx, __shfl_xor(mx, off));
  float ex = __expf(acc - mx);
  float sum = ex;
#pragma unroll
  for (int off = 32; off > 0; off >>= 1) sum += __shfl_xor(sum, off);
  out[(long)b*OO + o] = acc - mx - __logf(sum);
  for (int j = o; j < HH; j += 64)
    out[(long)BB*OO + (long)b*HH + j] = hbn[j];
}

// ---------------------------------------------------------------------------
extern "C" void kernel_launch(void* const* d_in, const int* in_sizes, int n_in,
                              void* d_out, int out_size, void* d_ws, size_t ws_size,
                              hipStream_t stream) {
  const float* x     = (const float*)d_in[0];
  const float* delta = (const float*)d_in[1];
  const float* mm    = (const float*)d_in[2];
  const float* xf    = (const float*)d_in[3];
  const int*   bs    = (const int*)  d_in[4];
  const float* W_r   = (const float*)d_in[5];
  const float* U_r   = (const float*)d_in[6];
  const float* V_r   = (const float*)d_in[7];
  const float* b_r   = (const float*)d_in[8];
  const float* W_z   = (const float*)d_in[9];
  const float* U_z   = (const float*)d_in[10];
  const float* V_z   = (const float*)d_in[11];
  const float* b_z   = (const float*)d_in[12];
  const float* W     = (const float*)d_in[13];
  const float* U     = (const float*)d_in[14];
  const float* V     = (const float*)d_in[15];
  const float* b     = (const float*)d_in[16];
  const float* Wgx   = (const float*)d_in[17];
  const float* bgx   = (const float*)d_in[18];
  const float* Wgh   = (const float*)d_in[19];
  const float* bgh   = (const float*)d_in[20];
  const float* decW  = (const float*)d_in[21];
  const float* decb  = (const float*)d_in[22];
  const float* bnw   = (const float*)d_in[23];
  const float* bnb   = (const float*)d_in[24];

  auto rnd = [](size_t v) { return (v + 255) & ~(size_t)255; };
  const size_t fixed_bytes = rnd((size_t)2048*256*2) + rnd(2048*4)
                           + rnd((size_t)256*1024) + rnd((size_t)128*1024)
                           + rnd(1536*4) + rnd(64)
                           + rnd((size_t)BB*HH*4);
  int TC = 0;
  const int cands[5] = {128, 64, 32, 16, 8};
  for (int i = 0; i < 5; ++i) {
    size_t need = fixed_bytes + rnd((size_t)BB*cands[i]*KK*2) + rnd((size_t)BB*cands[i]*NN*2);
    if (need <= ws_size) { TC = cands[i]; break; }
  }
  if (TC == 0) return;

  char* p = (char*)d_ws;
  auto alloc = [&](size_t bytes) { char* r = p; p += (bytes + 255) & ~(size_t)255; return r; };
  unsigned short* A_chunk = (unsigned short*)alloc((size_t)BB * TC * KK * 2);
  unsigned short* PREc    = (unsigned short*)alloc((size_t)BB * TC * NN * 2);
  unsigned short* BwT     = (unsigned short*)alloc((size_t)2048 * 256 * 2);
  float*          bias    = (float*)alloc(2048 * 4);
  unsigned int*   UzrN    = (unsigned int*)alloc((size_t)256 * 1024);
  unsigned int*   UhN     = (unsigned int*)alloc((size_t)128 * 1024);
  float*          uscale  = (float*)alloc(1536 * 4);
  float*          sbuf    = (float*)alloc(64);
  float*          h_st    = (float*)alloc((size_t)BB * HH * 4);

  prep_scales_kernel<<<6, 256, 0, stream>>>(U_z, U_r, U, uscale);
  prep_kernel<<<2440, 256, 0, stream>>>(W_z, V_z, b_z, W_r, V_r, b_r, W, V, b,
                                        Wgh, bgh, U_z, U_r, U, uscale,
                                        BwT, bias, UzrN, UhN);
  const int nch = TT / TC;
  for (int c = 0; c < nch; ++c) {
    int t0 = c * TC;
    build_A_kernel<<<BB*TC/8, 256, 0, stream>>>(x, delta, mm, xf, Wgx, bgx, bs,
                                                A_chunk, t0, TC);
    gemm1_kernel<<<(BB*TC/128)*16, 256, 0, stream>>>(A_chunk, BwT, bias, bs,
                                                     PREc, t0, TC);
    scan_kernel<<<16, 512, 0, stream>>>(PREc, UzrN, UhN, uscale, bs,
                                        h_st, sbuf, t0, TC);
  }
  head_kernel<<<256, 64, 0, stream>>>(h_st, decW, decb, bnw, bnb, (float*)d_out);
}

// Round 15
// 22345.628 us; speedup vs baseline: 1.1233x; 1.0210x over previous
//
#include <hip/hip_runtime.h>
#include <hip/hip_bf16.h>

typedef __attribute__((ext_vector_type(8))) short bf16x8;
typedef __attribute__((ext_vector_type(4))) float f32x4;
typedef __attribute__((ext_vector_type(4))) float fvec4;
typedef __attribute__((ext_vector_type(4))) unsigned short u16x4;
typedef __attribute__((ext_vector_type(4))) int i32x4;
typedef __attribute__((ext_vector_type(2))) unsigned int u32x2;

#define DEVI __device__ __forceinline__

constexpr int BB = 256, TT = 1024, FF = 128, HH = 512, OO = 64;
constexpr int KK = 256;    // fused input width [x_imp | m]
constexpr int NN = 2048;   // fused gate width  [z | r | htilde | gamma_h]

DEVI unsigned short f2bf(float x) {
  unsigned int u = __float_as_uint(x);
  u += 0x7FFFu + ((u >> 16) & 1u);          // RNE
  return (unsigned short)(u >> 16);
}
DEVI float bf2f(unsigned short s) {
  return __uint_as_float(((unsigned int)s) << 16);
}

DEVI void gload16(const void* g, void* lds) {
  __builtin_amdgcn_global_load_lds(
      (const __attribute__((address_space(1))) void*)g,
      (__attribute__((address_space(3))) void*)lds, 16, 0, 0);
}

DEVI void barrier_lds() {       // raw barrier: waits LDS ops only, vmcnt SURVIVES
  asm volatile("s_waitcnt lgkmcnt(0)" ::: "memory");
  __builtin_amdgcn_s_barrier();
  __builtin_amdgcn_sched_barrier(0);
}

// slabHG address swizzle (shorts): involution within a row, applied on BOTH
// the stage source and every read/write.
DEVI int hgIdx(int row, int c) { return row*1024 + (c ^ ((row & 7) << 3)); }

// ---------------------------------------------------------------------------
// K0a: per-column scales s_n = max_k |U[k][n]|  (z:0..511, r:512..1023, h:1024..1535)
// ---------------------------------------------------------------------------
__global__ __launch_bounds__(256) void prep_scales_kernel(
    const float* __restrict__ U_z, const float* __restrict__ U_r,
    const float* __restrict__ Uh, float* __restrict__ uscale)
{
  int n = blockIdx.x * 256 + threadIdx.x;
  if (n >= 1536) return;
  const float* src = (n < 512) ? U_z : (n < 1024) ? U_r : Uh;
  int col = n & 511;
  float s = 0.f;
  for (int k = 0; k < HH; ++k) s = fmaxf(s, fabsf(src[k*HH + col]));
  uscale[n] = fmaxf(s, 1e-30f);
}

// ---------------------------------------------------------------------------
// K0b: pack weights.
//   BwT [2048][256] bf16, bias[2048] f32 (as before)
//   UzrN u4 [16 u][8 wv][4 i][64 l][2 c] words (unit u = kt*2+half; half0=Uz)
//   UhN  u4 [ 8 u][8 wv][4 i][64 l][2 c] words (unit u = kt)
//   Word (…,c): nibble p = value q+8 at j = c*8 + (p&1)*4 + (p>>1),
//   k = base_k + (l>>4)*16 + j, col = (wv*4+i)*16 + (l&15),
//   q = clamp(round(U/s_col*7), -7, 7). Unpack = W&0x0F0F0F0F / (W>>4)&…
// ---------------------------------------------------------------------------
__global__ __launch_bounds__(256) void prep_kernel(
    const float* __restrict__ W_z, const float* __restrict__ V_z, const float* __restrict__ b_z,
    const float* __restrict__ W_r, const float* __restrict__ V_r, const float* __restrict__ b_r,
    const float* __restrict__ Wh,  const float* __restrict__ Vh,  const float* __restrict__ bh,
    const float* __restrict__ Wgh, const float* __restrict__ bgh,
    const float* __restrict__ U_z, const float* __restrict__ U_r, const float* __restrict__ Uh,
    const float* __restrict__ uscale,
    unsigned short* __restrict__ BwT, float* __restrict__ bias,
    unsigned int* __restrict__ UzrN, unsigned int* __restrict__ UhN)
{
  int idx = blockIdx.x * 256 + threadIdx.x;
  if (idx < 524288) {                       // BwT
    int n = idx >> 8, k = idx & 255;
    float v;
    if (n < 512)       { int h = n;        v = (k < 128) ? W_z[k*HH + h] : -V_z[(k-128)*HH + h]; }
    else if (n < 1024) { int h = n - 512;  v = (k < 128) ? W_r[k*HH + h] : -V_r[(k-128)*HH + h]; }
    else if (n < 1536) { int h = n - 1024; v = (k < 128) ? Wh [k*HH + h] : -Vh [(k-128)*HH + h]; }
    else               { int h = n - 1536; v = (k < 128) ? 0.f : Wgh[(k-128)*HH + h]; }
    BwT[n*256 + k] = f2bf(v);
    return;
  }
  idx -= 524288;
  if (idx < 2048) {                         // bias
    int n = idx; float v;
    if (n < 512)       { float s = b_z[n];      for (int f = 0; f < FF; ++f) s += V_z[f*HH + n];        v = s; }
    else if (n < 1024) { int h = n-512;  float s = b_r[h]; for (int f = 0; f < FF; ++f) s += V_r[f*HH + h]; v = s; }
    else if (n < 1536) { int h = n-1024; float s = bh[h];  for (int f = 0; f < FF; ++f) s += Vh[f*HH + h];  v = s; }
    else               { v = bgh[n-1536]; }
    bias[n] = v;
    return;
  }
  idx -= 2048;
  if (idx < 65536) {                        // UzrN words (i4, permuted, +8)
    int c  = idx & 1;
    int l  = (idx >> 1) & 63;
    int i  = (idx >> 7) & 3;
    int wv = (idx >> 9) & 7;
    int u  = idx >> 12;                    // 0..15
    int kt = u >> 1, half = u & 1;
    int col = (wv*4 + i)*16 + (l & 15);
    const float* src = half ? U_r : U_z;
    float sc = 7.f / uscale[half*512 + col];
    unsigned int word = 0;
#pragma unroll
    for (int p = 0; p < 8; ++p) {
      int j = c*8 + (p & 1)*4 + (p >> 1);
      int k = kt*64 + (l >> 4)*16 + j;
      float q = fminf(fmaxf(rintf(src[k*HH + col] * sc), -7.f), 7.f);
      unsigned int uq = (unsigned int)((int)q + 8);
      word |= (uq & 0xF) << (4*p);
    }
    UzrN[idx] = word;
    return;
  }
  idx -= 65536;
  if (idx < 32768) {                        // UhN words (i4, permuted, +8)
    int c  = idx & 1;
    int l  = (idx >> 1) & 63;
    int i  = (idx >> 7) & 3;
    int wv = (idx >> 9) & 7;
    int u  = idx >> 12;                    // 0..7 (kt)
    int col = (wv*4 + i)*16 + (l & 15);
    float sc = 7.f / uscale[1024 + col];
    unsigned int word = 0;
#pragma unroll
    for (int p = 0; p < 8; ++p) {
      int j = c*8 + (p & 1)*4 + (p >> 1);
      int k = u*64 + (l >> 4)*16 + j;
      float q = fminf(fmaxf(rintf(Uh[k*HH + col] * sc), -7.f), 7.f);
      unsigned int uq = (unsigned int)((int)q + 8);
      word |= (uq & 0xF) << (4*p);
    }
    UhN[idx] = word;
  }
}

// ---------------------------------------------------------------------------
// K1: imputation + fused A chunk [B*TC][256] bf16 = [x_imp | m]
// ---------------------------------------------------------------------------
__global__ __launch_bounds__(256) void build_A_kernel(
    const float* __restrict__ x, const float* __restrict__ delta,
    const float* __restrict__ mm, const float* __restrict__ xf,
    const float* __restrict__ Wgx, const float* __restrict__ bgx,
    const int* __restrict__ bs, unsigned short* __restrict__ A,
    int t0, int TC)
{
  int blk = blockIdx.x;
  int row8 = blk * 8;
  int b0  = row8 / TC;
  int tl0 = row8 % TC;
  if (b0 >= bs[t0 + tl0]) return;
  int tid = threadIdx.x;
  int rl = row8 + (tid >> 5);
  int tc = tl0 + (tid >> 5);
  long gi = ((long)b0*TT + t0 + tc) * 32 + (tid & 31);
  int f0 = (tid & 31) * 4;
  fvec4 xv = ((const fvec4*)x)[gi];
  fvec4 dv = ((const fvec4*)delta)[gi];
  fvec4 mv = ((const fvec4*)mm)[gi];
  fvec4 fv = ((const fvec4*)xf)[gi];
  unsigned short ox[4], om[4];
#pragma unroll
  for (int j = 0; j < 4; ++j) {
    float g  = __expf(-fmaxf(dv[j]*Wgx[f0+j] + bgx[f0+j], 0.f));
    float xr = g*fv[j] + (1.f - g)*0.001f;
    float xi = (mv[j] > 0.5f) ? xr : xv[j];
    ox[j] = f2bf(xi); om[j] = f2bf(mv[j]);
  }
  *(u16x4*)(A + (long)rl*KK + f0)       = (u16x4){ox[0], ox[1], ox[2], ox[3]};
  *(u16x4*)(A + (long)rl*KK + 128 + f0) = (u16x4){om[0], om[1], om[2], om[3]};
}

// ---------------------------------------------------------------------------
// K2: chunk GEMM  PRE[m][n] = A[m][:] @ Bw[:,n] + bias[n]  (bf16 MFMA, K=256)
// ---------------------------------------------------------------------------
__global__ __launch_bounds__(256) void gemm1_kernel(
    const unsigned short* __restrict__ A, const unsigned short* __restrict__ BwT,
    const float* __restrict__ bias, const int* __restrict__ bs,
    unsigned short* __restrict__ PRE, int t0, int TC)
{
  int blk = blockIdx.x;
  int nt = blk & 15;
  int mt = blk >> 4;
  {
    int m0 = mt * 128;
    int b_ = m0 / TC;
    int bcheck = (TC >= 128) ? bs[t0 + (m0 % TC)] : bs[t0];
    if (b_ >= bcheck) return;
  }
  int tid = threadIdx.x;
  int w = tid >> 6, l = tid & 63;
  int wm = w >> 1, wn = w & 1;
  int lr = l & 15, lg = l >> 4;
  int m_base = mt*128 + wm*64;
  int n_base = nt*128 + wn*64;
  const unsigned short* Aptr = A   + (long)(m_base + lr)*KK + lg*8;
  const unsigned short* Bptr = BwT + (long)(n_base + lr)*KK + lg*8;
  f32x4 acc[4][4];
#pragma unroll
  for (int i = 0; i < 4; ++i)
#pragma unroll
    for (int j = 0; j < 4; ++j) acc[i][j] = (f32x4){0.f, 0.f, 0.f, 0.f};

#pragma unroll
  for (int kt = 0; kt < 8; ++kt) {
    bf16x8 af[4], bfr[4];
#pragma unroll
    for (int i = 0; i < 4; ++i) af[i]  = *(const bf16x8*)(Aptr + (long)i*16*KK + kt*32);
#pragma unroll
    for (int i = 0; i < 4; ++i) bfr[i] = *(const bf16x8*)(Bptr + (long)i*16*KK + kt*32);
#pragma unroll
    for (int ms = 0; ms < 4; ++ms)
#pragma unroll
      for (int ns = 0; ns < 4; ++ns)
        acc[ms][ns] = __builtin_amdgcn_mfma_f32_16x16x32_bf16(af[ms], bfr[ns], acc[ms][ns], 0, 0, 0);
  }
#pragma unroll
  for (int ms = 0; ms < 4; ++ms) {
    int gm0 = m_base + ms*16 + lg*4;
#pragma unroll
    for (int ns = 0; ns < 4; ++ns) {
      int gn = n_base + ns*16 + lr;
      float bv = bias[gn];
      bool is_gamma = (gn >= 1536);
#pragma unroll
      for (int q = 0; q < 4; ++q) {
        float v = acc[ms][ns][q] + bv;
        if (is_gamma) v = __expf(-fmaxf(v, 0.f));
        PRE[(long)(gm0 + q)*NN + gn] = f2bf(v);
      }
    }
  }
}

// ---------------------------------------------------------------------------
// K3: sequential scan, 16 blocks x 512 threads (8 waves), i8 MFMA (K=64).
//   ALL U in int4 nibbles (+8 offset): z/r streamed via depth-4 register
//   prefetch (VGPR loads); Uh via depth-4 glds pipeline (4 x 2KB slots) with
//   counted vmcnt. Offset corrected exactly via rowsum(hd_q)/rowsum(a2_q).
//   Stream: 256(zr) + 128(Uh) + 64(HG) + 32(pzr) = 480 KB/step.
//   [r11 configuration — validated best; r12/r13/r14 perturbations of the
//    barrier/phase structure all regressed it.]
// ---------------------------------------------------------------------------
__global__ __launch_bounds__(512, 2) void scan_kernel(
    const unsigned short* __restrict__ PRE,
    const unsigned int* __restrict__ UzrN,
    const unsigned int* __restrict__ UhN,
    const float* __restrict__ uscale,
    const int* __restrict__ bs,
    float* __restrict__ h_st,
    float* __restrict__ sbuf,
    int t0, int TC)
{
  __shared__ __align__(16) char Ubuf[8][4][2048];          // 64 KB (4-slot Uh dbuf)
  __shared__ __align__(16) i32x4 hd_l[8*64];               // 8 KB hd / a2 frags
  __shared__ __align__(16) unsigned short slabHG[16*1024]; // 32 KB [row][htld|r : gamma]
  __shared__ float hm[16][524];                            // 33.5 KB h master
  __shared__ int hsumW[8][16];                             // hd rowsum partials
  __shared__ int hsumW2[8][16];                            // a2 rowsum partials
  __shared__ float wmax[8];

  const int tid = threadIdx.x;
  const int r0 = blockIdx.x * 16;
  if (t0 > 0 && bs[t0] <= r0) return;

  const int w = tid >> 6, l = tid & 63, lr = l & 15, lg = l >> 4;
  const size_t rowStr = (size_t)TC * NN;

  auto STAGEB = [&](int u) {   // Uh unit u (2 KB): 2 glds of 16B/lane
    const char* src = (const char*)UhN + ((size_t)(u*8 + w))*2048 + (size_t)l*16;
    char* dst = &Ubuf[w][u & 3][0];
    gload16(src, dst);
    gload16(src + 1024, dst + 1024);
  };
  auto STAGEHG = [&](const unsigned short* PREn) {  // htilde+gamma halves, swizzled source
#pragma unroll
    for (int j = 0; j < 4; ++j) {
      int idx = w*4 + j;
      int row = idx >> 1;
      int phys = (idx & 1)*512 + l*8;
      int logi = phys ^ ((row & 7) << 3);
      const unsigned short* src = PREn + (size_t)row*rowStr + 1024 + logi;
      gload16(src, &slabHG[idx*512]);
    }
  };
  auto LOADZR = [&](int u, u32x2* d) {   // z/r unit u: 4 tiles x 8B per thread
#pragma unroll
    for (int i = 0; i < 4; ++i)
      d[i] = ((const u32x2*)UzrN)[(u*8 + w)*256 + i*64 + l];
  };

  // per-thread dequant constants
  float zdq[4], rdq[4], hdq[4];
#pragma unroll
  for (int i = 0; i < 4; ++i) {
    int c = (w*4 + i)*16 + lr;
    zdq[i] = uscale[c]        * (1.f/889.f);    // 7 * 127
    rdq[i] = uscale[512 + c]  * (1.f/889.f);
    hdq[i] = uscale[1024 + c] * (1.f/889.f);
  }
  if (tid < 8) wmax[tid] = (t0 == 0) ? 1e-20f : sbuf[blockIdx.x];

  if (t0 == 0) {
    for (int i = tid; i < 16*512; i += 512) hm[i>>9][i&511] = 0.f;
  } else {
    for (int i = tid; i < 16*512; i += 512)
      hm[i>>9][i&511] = h_st[(size_t)(r0 + (i>>9))*HH + (i&511)];
  }
  asm volatile("s_waitcnt vmcnt(0)" ::: "memory");  // hm loads fully done
  __builtin_amdgcn_sched_barrier(0);

  // prologue staging: HG(step 0), B0, B1  (8 loads outstanding)
  STAGEHG(PRE + (size_t)r0*TC*NN);
  STAGEB(0); STAGEB(1);

  for (int tc = 0; tc < TC; ++tc) {
    const int bsv = bs[t0 + tc];
    if (bsv <= r0) break;                  // descending bs: done forever
    const int na = min(16, bsv - r0);
    const unsigned short* PREstep = PRE + ((size_t)r0*TC + tc)*NN;
    const unsigned short* PREnext = PREstep + NN;

    barrier_lds();                         // S1: prev hm + wmax writes visible
    asm volatile("s_waitcnt vmcnt(4)" ::: "memory");  // HG landed; B0,B1 fly
    __builtin_amdgcn_sched_barrier(0);

    // dynamic quant scale for hd (exact bound: |hd| <= max|h| = s)
    float s = wmax[0];
#pragma unroll
    for (int i = 1; i < 8; ++i) s = fmaxf(s, wmax[i]);
    const float qs = 127.f / s;

    // pz/pr clump (VGPR loads, consumed in epilogue A)
    unsigned short pzr[2][4][4];
#pragma unroll
    for (int i = 0; i < 4; ++i)
#pragma unroll
      for (int q = 0; q < 4; ++q) {
        int row = lg*4 + q, col = (w*4 + i)*16 + lr;
        const unsigned short* pb = PREstep + (size_t)row*rowStr + col;
        pzr[0][i][q] = pb[0];
        pzr[1][i][q] = pb[512];
      }

    // prefetch z/r units 0..3 into registers (depth-4)
    u32x2 inW[4][4];
    LOADZR(0, inW[0]); LOADZR(1, inW[1]);
    LOADZR(2, inW[2]); LOADZR(3, inW[3]);

    // hd build (kt = w): quantize (act? gamma*h : h) to i8 frags + rowsum
    i32x4 qwReg;
    {
      const int k0 = w*64 + lg*16;
      const bool act = lr < na;
      bf16x8 g0 = *(const bf16x8*)&slabHG[hgIdx(lr, 512 + k0)];
      bf16x8 g1 = *(const bf16x8*)&slabHG[hgIdx(lr, 512 + k0 + 8)];
      int psum = 0;
#pragma unroll
      for (int d = 0; d < 4; ++d) {
        int word = 0;
#pragma unroll
        for (int b = 0; b < 4; ++b) {
          int j = d*4 + b;
          float h  = hm[lr][k0 + j];
          float gv = bf2f((unsigned short)(j < 8 ? g0[j] : g1[j-8]));
          float hd = act ? gv*h : h;
          int qi = (int)rintf(hd*qs);
          psum += qi;
          word |= (qi & 0xFF) << (8*b);
        }
        qwReg[d] = word;
      }
      hd_l[w*64 + l] = qwReg;
      psum += __shfl_xor(psum, 16);
      psum += __shfl_xor(psum, 32);
      if (lg == 0) hsumW[w][lr] = psum;    // wave w's k-range [64w, 64w+64)
    }

    // hoist htilde-preact + gamma for my output cells (before r overwrites)
    float phv[4][4], ggv[4][4];
#pragma unroll
    for (int i = 0; i < 4; ++i)
#pragma unroll
      for (int q = 0; q < 4; ++q) {
        int row = lg*4 + q, col = (w*4 + i)*16 + lr;
        phv[i][q] = bf2f(slabHG[hgIdx(row, col)]);
        ggv[i][q] = bf2f(slabHG[hgIdx(row, 512 + col)]);
      }
    barrier_lds();                         // S2: hd_l + hsumW ready

    // ---- phase A: z|r, 16 units, depth-4 register-streamed i4 ----
    i32x4 acc[8];
#pragma unroll
    for (int i = 0; i < 8; ++i) acc[i] = (i32x4){0, 0, 0, 0};
    i32x4 af;
#pragma unroll
    for (int u = 0; u < 16; ++u) {
      if (!(u & 1)) af = hd_l[(u>>1)*64 + l];
      u32x2* inw = inW[u & 3];
      __builtin_amdgcn_s_setprio(1);
#pragma unroll
      for (int i = 0; i < 4; ++i) {
        unsigned int W0 = inw[i][0], W1 = inw[i][1];
        i32x4 bfr;
        bfr[0] = (int)(W0 & 0x0F0F0F0Fu);
        bfr[1] = (int)((W0 >> 4) & 0x0F0F0F0Fu);
        bfr[2] = (int)(W1 & 0x0F0F0F0Fu);
        bfr[3] = (int)((W1 >> 4) & 0x0F0F0F0Fu);
        acc[(u&1)*4 + i] = __builtin_amdgcn_mfma_i32_16x16x64_i8(af, bfr, acc[(u&1)*4 + i], 0, 0, 0);
      }
      __builtin_amdgcn_s_setprio(0);
      if (u < 12) LOADZR(u + 4, inW[u & 3]);
    }
    // stage Uh units 2,3 now (covered by epilogue A + a2 build)
    STAGEB(2); STAGEB(3);

    // epilogue A: offset-correct, z -> regs; r -> slabHG (cols 0..511)
    int rsum[4];
#pragma unroll
    for (int q = 0; q < 4; ++q) {
      int row = lg*4 + q, t = 0;
#pragma unroll
      for (int w2 = 0; w2 < 8; ++w2) t += hsumW[w2][row];
      rsum[q] = t * 8;
    }
    float zreg[4][4];
#pragma unroll
    for (int i = 0; i < 4; ++i)
#pragma unroll
      for (int q = 0; q < 4; ++q) {
        int row = lg*4 + q, col = (w*4 + i)*16 + lr;
        float az = bf2f(pzr[0][i][q]) + (float)(acc[i][q]   - rsum[q]) * zdq[i] * s;
        float ar = bf2f(pzr[1][i][q]) + (float)(acc[4+i][q] - rsum[q]) * rdq[i] * s;
        zreg[i][q] = 1.f/(1.f + __expf(-az));
        slabHG[hgIdx(row, col)] = f2bf(1.f/(1.f + __expf(-ar)));
      }
    barrier_lds();                         // S3: r ready; phase-A hd_l reads done

    // a2 = hd*r quantized (register hd; same slot rewrite) + a2 rowsum
    {
      const int k0 = w*64 + lg*16;
      bf16x8 r0v = *(const bf16x8*)&slabHG[hgIdx(lr, k0)];
      bf16x8 r1v = *(const bf16x8*)&slabHG[hgIdx(lr, k0 + 8)];
      i32x4 nw;
      int psum2 = 0;
#pragma unroll
      for (int d = 0; d < 4; ++d) {
        int word = qwReg[d], out = 0;
#pragma unroll
        for (int b = 0; b < 4; ++b) {
          int j = d*4 + b;
          int hq = (int)(signed char)((word >> (8*b)) & 0xFF);
          float rv = bf2f((unsigned short)(j < 8 ? r0v[j] : r1v[j-8]));
          int qi = (int)rintf((float)hq * rv);
          psum2 += qi;
          out |= (qi & 0xFF) << (8*b);
        }
        nw[d] = out;
      }
      hd_l[w*64 + l] = nw;
      psum2 += __shfl_xor(psum2, 16);
      psum2 += __shfl_xor(psum2, 32);
      if (lg == 0) hsumW2[w][lr] = psum2;
    }
    barrier_lds();                         // S4: a2 frags + hsumW2 ready

    // ---- phase B: htilde, 8 units, depth-4 glds i4 ----
    // FIFO worst case at entry: [B0,B1,B2,B3] = 8 loads.
    i32x4 accB[4];
#pragma unroll
    for (int i = 0; i < 4; ++i) accB[i] = (i32x4){0, 0, 0, 0};
#pragma unroll
    for (int u = 0; u < 8; ++u) {
      if (u < 5) { asm volatile("s_waitcnt vmcnt(6)" ::: "memory"); }
      else       { asm volatile("s_waitcnt vmcnt(8)" ::: "memory"); }
      __builtin_amdgcn_sched_barrier(0);
      const char* buf = &Ubuf[w][u & 3][0];
      i32x4 af2 = hd_l[u*64 + l];
      __builtin_amdgcn_s_setprio(1);
#pragma unroll
      for (int i = 0; i < 4; ++i) {
        u32x2 Wv = *(const u32x2*)&buf[(i*64 + l)*8];
        unsigned int W0 = Wv[0], W1 = Wv[1];
        i32x4 bfr;
        bfr[0] = (int)(W0 & 0x0F0F0F0Fu);
        bfr[1] = (int)((W0 >> 4) & 0x0F0F0F0Fu);
        bfr[2] = (int)(W1 & 0x0F0F0F0Fu);
        bfr[3] = (int)((W1 >> 4) & 0x0F0F0F0Fu);
        accB[i] = __builtin_amdgcn_mfma_i32_16x16x64_i8(af2, bfr, accB[i], 0, 0, 0);
      }
      __builtin_amdgcn_s_setprio(0);
      __builtin_amdgcn_sched_barrier(0);
      if (u < 4)       STAGEB(u + 4);      // B4..B7 -> slots 0..3 (just freed)
      else if (u == 4) STAGEHG(PREnext);
      else if (u == 5) STAGEB(0);          // next step's B0
      else if (u == 6) STAGEB(1);          // next step's B1
    }

    // epilogue B: h update + block max|h| for next step's quant scale
    int rsum2[4];
#pragma unroll
    for (int q = 0; q < 4; ++q) {
      int row = lg*4 + q, t = 0;
#pragma unroll
      for (int w2 = 0; w2 < 8; ++w2) t += hsumW2[w2][row];
      rsum2[q] = t * 8;
    }
    float mloc = 0.f;
#pragma unroll
    for (int i = 0; i < 4; ++i)
#pragma unroll
      for (int q = 0; q < 4; ++q) {
        int row = lg*4 + q, col = (w*4 + i)*16 + lr;
        float hval;
        if (row < na) {
          float ah = phv[i][q] + (float)(accB[i][q] - rsum2[q]) * hdq[i] * s;
          float e  = __expf(2.f*ah);
          float th = 1.f - 2.f/(e + 1.f);          // tanh, overflow-safe
          float hd = ggv[i][q] * hm[row][col];
          hval = hd + zreg[i][q]*(th - hd);
          hm[row][col] = hval;
        } else {
          hval = hm[row][col];
        }
        mloc = fmaxf(mloc, fabsf(hval));
      }
#pragma unroll
    for (int off = 32; off > 0; off >>= 1) mloc = fmaxf(mloc, __shfl_xor(mloc, off));
    if (l == 0) wmax[w] = fmaxf(mloc, 1e-20f);
  }

  asm volatile("s_waitcnt vmcnt(0)" ::: "memory");  // drain stray prefetches
  barrier_lds();
  for (int i = tid; i < 16*512; i += 512)
    h_st[(size_t)(r0 + (i>>9))*HH + (i&511)] = hm[i>>9][i&511];
  if (tid == 0) {
    float s = wmax[0];
#pragma unroll
    for (int i = 1; i < 8; ++i) s = fmaxf(s, wmax[i]);
    sbuf[blockIdx.x] = s;
  }
}

// ---------------------------------------------------------------------------
// K4: head: eval BatchNorm + decoder GEMV + log_softmax.
//   d_out = [output (256x64) | h_bn (256x512)] fp32
// ---------------------------------------------------------------------------
__global__ __launch_bounds__(64) void head_kernel(
    const float* __restrict__ h_state, const float* __restrict__ decW,
    const float* __restrict__ decb, const float* __restrict__ bnw,
    const float* __restrict__ bnb, float* __restrict__ out)
{
  int b = blockIdx.x, o = threadIdx.x;
  __shared__ float hbn[HH];
  const float s = rsqrtf(1.f + 1e-5f);
  for (int j = o; j < HH; j += 64)
    hbn[j] = h_state[(long)b*HH + j] * (bnw[j] * s) + bnb[j];
  __syncthreads();
  float acc = decb[o];
  for (int j = 0; j < HH; ++j) acc += hbn[j] * decW[j*OO + o];
  float mx = acc;
#pragma unroll
  for (int off = 32; off > 0; off >>= 1) mx = fmaxf(mx, __shfl_xor(mx, off));
  float ex = __expf(acc - mx);
  float sum = ex;
#pragma unroll
  for (int off = 32; off > 0; off >>= 1) sum += __shfl_xor(sum, off);
  out[(long)b*OO + o] = acc - mx - __logf(sum);
  for (int j = o; j < HH; j += 64)
    out[(long)BB*OO + (long)b*HH + j] = hbn[j];
}

// ---------------------------------------------------------------------------
extern "C" void kernel_launch(void* const* d_in, const int* in_sizes, int n_in,
                              void* d_out, int out_size, void* d_ws, size_t ws_size,
                              hipStream_t stream) {
  const float* x     = (const float*)d_in[0];
  const float* delta = (const float*)d_in[1];
  const float* mm    = (const float*)d_in[2];
  const float* xf    = (const float*)d_in[3];
  const int*   bs    = (const int*)  d_in[4];
  const float* W_r   = (const float*)d_in[5];
  const float* U_r   = (const float*)d_in[6];
  const float* V_r   = (const float*)d_in[7];
  const float* b_r   = (const float*)d_in[8];
  const float* W_z   = (const float*)d_in[9];
  const float* U_z   = (const float*)d_in[10];
  const float* V_z   = (const float*)d_in[11];
  const float* b_z   = (const float*)d_in[12];
  const float* W     = (const float*)d_in[13];
  const float* U     = (const float*)d_in[14];
  const float* V     = (const float*)d_in[15];
  const float* b     = (const float*)d_in[16];
  const float* Wgx   = (const float*)d_in[17];
  const float* bgx   = (const float*)d_in[18];
  const float* Wgh   = (const float*)d_in[19];
  const float* bgh   = (const float*)d_in[20];
  const float* decW  = (const float*)d_in[21];
  const float* decb  = (const float*)d_in[22];
  const float* bnw   = (const float*)d_in[23];
  const float* bnb   = (const float*)d_in[24];

  auto rnd = [](size_t v) { return (v + 255) & ~(size_t)255; };
  const size_t fixed_bytes = rnd((size_t)2048*256*2) + rnd(2048*4)
                           + rnd((size_t)256*1024) + rnd((size_t)128*1024)
                           + rnd(1536*4) + rnd(64)
                           + rnd((size_t)BB*HH*4);
  int TC = 0;
  const int cands[5] = {128, 64, 32, 16, 8};
  for (int i = 0; i < 5; ++i) {
    size_t need = fixed_bytes + rnd((size_t)BB*cands[i]*KK*2) + rnd((size_t)BB*cands[i]*NN*2);
    if (need <= ws_size) { TC = cands[i]; break; }
  }
  if (TC == 0) return;

  char* p = (char*)d_ws;
  auto alloc = [&](size_t bytes) { char* r = p; p += (bytes + 255) & ~(size_t)255; return r; };
  unsigned short* A_chunk = (unsigned short*)alloc((size_t)BB * TC * KK * 2);
  unsigned short* PREc    = (unsigned short*)alloc((size_t)BB * TC * NN * 2);
  unsigned short* BwT     = (unsigned short*)alloc((size_t)2048 * 256 * 2);
  float*          bias    = (float*)alloc(2048 * 4);
  unsigned int*   UzrN    = (unsigned int*)alloc((size_t)256 * 1024);
  unsigned int*   UhN     = (unsigned int*)alloc((size_t)128 * 1024);
  float*          uscale  = (float*)alloc(1536 * 4);
  float*          sbuf    = (float*)alloc(64);
  float*          h_st    = (float*)alloc((size_t)BB * HH * 4);

  prep_scales_kernel<<<6, 256, 0, stream>>>(U_z, U_r, U, uscale);
  prep_kernel<<<2440, 256, 0, stream>>>(W_z, V_z, b_z, W_r, V_r, b_r, W, V, b,
                                        Wgh, bgh, U_z, U_r, U, uscale,
                                        BwT, bias, UzrN, UhN);
  const int nch = TT / TC;
  for (int c = 0; c < nch; ++c) {
    int t0 = c * TC;
    build_A_kernel<<<BB*TC/8, 256, 0, stream>>>(x, delta, mm, xf, Wgx, bgx, bs,
                                                A_chunk, t0, TC);
    gemm1_kernel<<<(BB*TC/128)*16, 256, 0, stream>>>(A_chunk, BwT, bias, bs,
                                                     PREc, t0, TC);
    scan_kernel<<<16, 512, 0, stream>>>(PREc, UzrN, UhN, uscale, bs,
                                        h_st, sbuf, t0, TC);
  }
  head_kernel<<<256, 64, 0, stream>>>(h_st, decW, decb, bnw, bnb, (float*)d_out);
}